// Round 1
// baseline (4251.534 us; speedup 1.0000x reference)
//
#include <hip/hip_runtime.h>

// Problem constants (fixed by the reference)
constexpr int NN  = 50000;   // nodes
constexpr int NNZ = 800000;  // edges per relation
constexpr int RR  = 3;       // relations
constexpr int D   = 128;     // feature dim (in == out)
constexpr float EPS = 1e-6f;

// ---------------------------------------------------------------------------
// Kernel 1: COO SpMM scatter.  support[r][row][:] += val * x[col][:]
// One 32-lane group per edge; each lane handles 4 contiguous floats (float4).
// ---------------------------------------------------------------------------
__global__ __launch_bounds__(256) void spmm_scatter(
    const float* __restrict__ x,      // [NN][D]
    const int*   __restrict__ rows,   // [RR*NNZ]
    const int*   __restrict__ cols,   // [RR*NNZ]
    const float* __restrict__ vals,   // [RR*NNZ]
    float* __restrict__ support) {    // [RR][NN][D]
  int gid = blockIdx.x * 256 + threadIdx.x;
  int e   = gid >> 5;                 // edge index
  if (e >= RR * NNZ) return;
  int l   = gid & 31;                 // lane-in-group: covers d = l*4 .. l*4+3
  int row = rows[e];
  int col = cols[e];
  float v = vals[e];
  float4 m = ((const float4*)(x + (size_t)col * D))[l];
  int r = e / NNZ;                    // relation (compiler -> magic mul)
  float* dst = support + ((size_t)r * NN + (size_t)row) * D + l * 4;
  unsafeAtomicAdd(dst + 0, m.x * v);
  unsafeAtomicAdd(dst + 1, m.y * v);
  unsafeAtomicAdd(dst + 2, m.z * v);
  unsafeAtomicAdd(dst + 3, m.w * v);
}

// ---------------------------------------------------------------------------
// Kernel 2: support_sum = s0+s1+s2 ; sn = LayerNorm(support_sum)
// One 64-lane wave per node (each lane owns 2 features). sn written to d_out
// (scratch reuse; GEMM reads its own rows before overwriting them).
// ---------------------------------------------------------------------------
__global__ __launch_bounds__(256) void sum_ln(
    const float* __restrict__ support,  // [RR][NN][D]
    const float* __restrict__ gamma,    // [D]
    const float* __restrict__ beta,     // [D]
    float* __restrict__ sn) {           // [NN][D]
  int node = blockIdx.x * 4 + (threadIdx.x >> 6);
  if (node >= NN) return;
  int l = threadIdx.x & 63;
  const float2* s0 = (const float2*)(support + (size_t)node * D);
  const float2* s1 = (const float2*)(support + ((size_t)NN + node) * D);
  const float2* s2 = (const float2*)(support + ((size_t)2 * NN + node) * D);
  float2 a = s0[l], b = s1[l], c = s2[l];
  float v0 = a.x + b.x + c.x;
  float v1 = a.y + b.y + c.y;
  float sum = v0 + v1;
  float sq  = v0 * v0 + v1 * v1;
  #pragma unroll
  for (int m = 32; m >= 1; m >>= 1) {
    sum += __shfl_xor(sum, m);
    sq  += __shfl_xor(sq,  m);
  }
  float mean = sum * (1.0f / D);
  float var  = sq * (1.0f / D) - mean * mean;
  float rstd = rsqrtf(var + EPS);
  int d = l * 2;
  float o0 = (v0 - mean) * rstd * gamma[d]     + beta[d];
  float o1 = (v1 - mean) * rstd * gamma[d + 1] + beta[d + 1];
  ((float2*)(sn + (size_t)node * D))[l] = make_float2(o0, o1);
}

// ---------------------------------------------------------------------------
// Kernel 3: fused GEMM.
//   out[n][j] = 0.5 * ( sum_{k<384} support[k/128][n][k%128] * weight[k][j]
//                     + sum_{k<128} sn[n][k] * shw[k][j] ) + bias[j]
// Tiled: BM=64 rows, BN=128 (full), BK=32. 256 threads, 8x4 micro-tile.
// ---------------------------------------------------------------------------
constexpr int BM = 64;
constexpr int BK = 32;

__global__ __launch_bounds__(256) void gemm_fused(
    const float* __restrict__ support,  // [RR][NN][D]
    const float* __restrict__ sn,       // [NN][D]   (lives in d_out)
    const float* __restrict__ weight,   // [RR*D][D]
    const float* __restrict__ shw,      // [D][D]
    const float* __restrict__ bias,     // [D]
    float* __restrict__ out) {          // [NN][D]
  __shared__ float As[BM][36];   // [row][k] padded: stride 36 floats (144B, 16B-aligned)
  __shared__ float Bs[BK][D];

  int tid = threadIdx.x;
  int bm0 = blockIdx.x * BM;
  int tn  = tid & 31;    // 32 thread-cols * 4 outputs = 128
  int tm  = tid >> 5;    // 8 thread-rows * 8 rows     = 64

  float acc[8][4];
  #pragma unroll
  for (int i = 0; i < 8; i++)
    #pragma unroll
    for (int j = 0; j < 4; j++) acc[i][j] = 0.f;

  for (int kc = 0; kc < 16; kc++) {
    int k0 = kc * BK;
    const float* Asrc;
    int d0;
    if (k0 < 384) { Asrc = support + (size_t)(k0 >> 7) * NN * D; d0 = k0 & 127; }
    else          { Asrc = sn;                                    d0 = k0 - 384; }
    const float* Bsrc = (k0 < 384) ? (weight + (size_t)k0 * D)
                                   : (shw + (size_t)(k0 - 384) * D);

    // A tile: 64 rows x 32 k = 512 float4 loads, 2 per thread
    #pragma unroll
    for (int t = 0; t < 2; t++) {
      int f   = t * 256 + tid;       // 0..511
      int row = f >> 3;              // 0..63
      int kk4 = (f & 7) * 4;         // 0..28
      int grow = bm0 + row;
      float4 va = make_float4(0.f, 0.f, 0.f, 0.f);
      if (grow < NN) va = *(const float4*)(Asrc + (size_t)grow * D + d0 + kk4);
      *(float4*)&As[row][kk4] = va;
    }
    // B tile: 32 k x 128 j = 1024 float4 loads, 4 per thread
    #pragma unroll
    for (int t = 0; t < 4; t++) {
      int f  = t * 256 + tid;        // 0..1023
      int kk = f >> 5;               // 0..31
      int j4 = (f & 31) * 4;         // 0..124
      float4 vb = *(const float4*)(Bsrc + (size_t)kk * D + j4);
      *(float4*)&Bs[kk][j4] = vb;
    }
    __syncthreads();

    #pragma unroll
    for (int k4 = 0; k4 < BK; k4 += 4) {
      float4 b0 = *(const float4*)&Bs[k4 + 0][tn * 4];
      float4 b1 = *(const float4*)&Bs[k4 + 1][tn * 4];
      float4 b2 = *(const float4*)&Bs[k4 + 2][tn * 4];
      float4 b3 = *(const float4*)&Bs[k4 + 3][tn * 4];
      #pragma unroll
      for (int i = 0; i < 8; i++) {
        float4 a = *(const float4*)&As[tm * 8 + i][k4];
        acc[i][0] += a.x * b0.x + a.y * b1.x + a.z * b2.x + a.w * b3.x;
        acc[i][1] += a.x * b0.y + a.y * b1.y + a.z * b2.y + a.w * b3.y;
        acc[i][2] += a.x * b0.z + a.y * b1.z + a.z * b2.z + a.w * b3.z;
        acc[i][3] += a.x * b0.w + a.y * b1.w + a.z * b2.w + a.w * b3.w;
      }
    }
    __syncthreads();
  }

  float4 bv = *(const float4*)&bias[tn * 4];
  #pragma unroll
  for (int i = 0; i < 8; i++) {
    int grow = bm0 + tm * 8 + i;
    if (grow < NN) {
      float4 o;
      o.x = 0.5f * acc[i][0] + bv.x;
      o.y = 0.5f * acc[i][1] + bv.y;
      o.z = 0.5f * acc[i][2] + bv.z;
      o.w = 0.5f * acc[i][3] + bv.w;
      *(float4*)&out[(size_t)grow * D + tn * 4] = o;
    }
  }
}

// ---------------------------------------------------------------------------
extern "C" void kernel_launch(void* const* d_in, const int* in_sizes, int n_in,
                              void* d_out, int out_size, void* d_ws, size_t ws_size,
                              hipStream_t stream) {
  const float* input  = (const float*)d_in[0];
  const int*   arows  = (const int*)  d_in[1];
  const int*   acols  = (const int*)  d_in[2];
  const float* avals  = (const float*)d_in[3];
  const float* weight = (const float*)d_in[4];
  const float* shw    = (const float*)d_in[5];
  const float* bias   = (const float*)d_in[6];
  const float* gamma  = (const float*)d_in[7];
  const float* beta   = (const float*)d_in[8];
  float* out = (float*)d_out;

  float* support = (float*)d_ws;                       // [RR][NN][D] = 76.8 MB
  size_t support_bytes = (size_t)RR * NN * D * sizeof(float);
  float* sn = out;                                     // reuse d_out as LN scratch

  hipMemsetAsync(support, 0, support_bytes, stream);

  {
    long long total_threads = (long long)RR * NNZ * 32;
    int blocks = (int)((total_threads + 255) / 256);
    spmm_scatter<<<blocks, 256, 0, stream>>>(input, arows, acols, avals, support);
  }
  {
    int blocks = (NN + 3) / 4;
    sum_ln<<<blocks, 256, 0, stream>>>(support, gamma, beta, sn);
  }
  {
    int blocks = (NN + BM - 1) / BM;
    gemm_fused<<<blocks, 256, 0, stream>>>(support, sn, weight, shw, bias, out);
  }
}

// Round 2
// 742.264 us; speedup vs baseline: 5.7278x; 5.7278x over previous
//
#include <hip/hip_runtime.h>

// Problem constants (fixed by the reference)
constexpr int NN  = 50000;   // nodes
constexpr int NNZ = 800000;  // edges per relation
constexpr int RR  = 3;       // relations
constexpr int D   = 128;     // feature dim (in == out)
constexpr int RN  = RR * NN; // buckets
constexpr int NE  = RR * NNZ;
constexpr float EPS = 1e-6f;

// ---------------------------------------------------------------------------
// K1: histogram of destination rows per relation. cnt[r*NN+row]++
// ---------------------------------------------------------------------------
__global__ __launch_bounds__(256) void hist_rows(
    const int* __restrict__ rows, int* __restrict__ cnt) {
  int e = blockIdx.x * 256 + threadIdx.x;
  if (e >= NE) return;
  int r = (e >= 2 * NNZ) ? 2 : (e >= NNZ ? 1 : 0);
  atomicAdd(&cnt[r * NN + rows[e]], 1);
}

// ---------------------------------------------------------------------------
// K2a: per-block local exclusive scan (1024 elems/block) + block sums
// ---------------------------------------------------------------------------
__global__ __launch_bounds__(256) void scan_local(
    const int* __restrict__ cnt, int* __restrict__ off, int* __restrict__ bsum) {
  __shared__ int sdata[256];
  int t = threadIdx.x;
  int base = blockIdx.x * 1024 + t * 4;
  int c[4];
  #pragma unroll
  for (int j = 0; j < 4; j++) c[j] = (base + j < RN) ? cnt[base + j] : 0;
  int s = c[0] + c[1] + c[2] + c[3];
  sdata[t] = s;
  __syncthreads();
  #pragma unroll
  for (int step = 1; step < 256; step <<= 1) {
    int v = (t >= step) ? sdata[t - step] : 0;
    __syncthreads();
    sdata[t] += v;
    __syncthreads();
  }
  int excl = sdata[t] - s;
  if (base + 0 < RN) off[base + 0] = excl;
  if (base + 1 < RN) off[base + 1] = excl + c[0];
  if (base + 2 < RN) off[base + 2] = excl + c[0] + c[1];
  if (base + 3 < RN) off[base + 3] = excl + c[0] + c[1] + c[2];
  if (t == 255) bsum[blockIdx.x] = sdata[255];
}

// ---------------------------------------------------------------------------
// K2b: inclusive scan of block sums (single wave, shfl scan with carry)
// ---------------------------------------------------------------------------
__global__ __launch_bounds__(64) void scan_bsums(int* __restrict__ bsum, int nb) {
  int l = threadIdx.x;
  int carry = 0;
  for (int base = 0; base < nb; base += 64) {
    int i = base + l;
    int v = (i < nb) ? bsum[i] : 0;
    #pragma unroll
    for (int s = 1; s < 64; s <<= 1) {
      int u = __shfl_up(v, s);
      if (l >= s) v += u;
    }
    int tot = __shfl(v, 63);
    if (i < nb) bsum[i] = v + carry;
    carry += tot;
  }
}

// ---------------------------------------------------------------------------
// K2c: apply block offsets; init cursors; write off[RN] = total
// ---------------------------------------------------------------------------
__global__ __launch_bounds__(256) void scan_apply(
    int* __restrict__ off, const int* __restrict__ bsum, int* __restrict__ cur, int nb) {
  int b = blockIdx.x;
  int add = (b > 0) ? bsum[b - 1] : 0;
  int base = b * 1024 + threadIdx.x * 4;
  #pragma unroll
  for (int j = 0; j < 4; j++) {
    int i = base + j;
    if (i < RN) {
      int v = off[i] + add;
      off[i] = v;
      cur[i] = v;
    }
  }
  if (b == 0 && threadIdx.x == 0) off[RN] = bsum[nb - 1];
}

// ---------------------------------------------------------------------------
// K3: fill sorted (col, val) pairs per bucket
// ---------------------------------------------------------------------------
__global__ __launch_bounds__(256) void fill_csr(
    const int* __restrict__ rows, const int* __restrict__ cols,
    const float* __restrict__ vals, int* __restrict__ cur,
    int2* __restrict__ epack) {
  int e = blockIdx.x * 256 + threadIdx.x;
  if (e >= NE) return;
  int r = (e >= 2 * NNZ) ? 2 : (e >= NNZ ? 1 : 0);
  int b = r * NN + rows[e];
  int pos = atomicAdd(&cur[b], 1);
  epack[pos] = make_int2(cols[e], __float_as_int(vals[e]));
}

// ---------------------------------------------------------------------------
// K4: gather SpMM for all 3 relations + sum + LayerNorm, fused.
// One 64-lane wave per node; each lane owns 2 feature dims (float2).
// Writes support[r][node][:] and sn[node][:] (sn lives in d_out).
// ---------------------------------------------------------------------------
__global__ __launch_bounds__(256) void gather_ln(
    const float* __restrict__ x,       // [NN][D]
    const int2*  __restrict__ epack,   // [NE] sorted by bucket
    const int*   __restrict__ off,     // [RN+1]
    const float* __restrict__ gamma,
    const float* __restrict__ beta,
    float* __restrict__ support,       // [RR][NN][D]
    float* __restrict__ sn) {          // [NN][D]
  int node = blockIdx.x * 4 + (threadIdx.x >> 6);
  if (node >= NN) return;
  int l = threadIdx.x & 63;
  float2 tot = make_float2(0.f, 0.f);
  #pragma unroll
  for (int r = 0; r < RR; r++) {
    int b = r * NN + node;
    int s = off[b], e = off[b + 1];
    float2 acc = make_float2(0.f, 0.f);
    for (int i = s; i < e; i++) {
      int2 p = epack[i];                     // broadcast load (same addr per wave)
      float v = __int_as_float(p.y);
      float2 xv = ((const float2*)(x + (size_t)p.x * D))[l];
      acc.x += v * xv.x;
      acc.y += v * xv.y;
    }
    ((float2*)(support + ((size_t)r * NN + node) * D))[l] = acc;
    tot.x += acc.x;
    tot.y += acc.y;
  }
  float sum = tot.x + tot.y;
  float sq  = tot.x * tot.x + tot.y * tot.y;
  #pragma unroll
  for (int m = 32; m >= 1; m >>= 1) {
    sum += __shfl_xor(sum, m);
    sq  += __shfl_xor(sq,  m);
  }
  float mean = sum * (1.0f / D);
  float var  = sq * (1.0f / D) - mean * mean;
  float rstd = rsqrtf(var + EPS);
  int d = l * 2;
  float o0 = (tot.x - mean) * rstd * gamma[d]     + beta[d];
  float o1 = (tot.y - mean) * rstd * gamma[d + 1] + beta[d + 1];
  ((float2*)(sn + (size_t)node * D))[l] = make_float2(o0, o1);
}

// ---------------------------------------------------------------------------
// K5: fused GEMM.
//   out[n][j] = 0.5*( sum_{k<384} support[k/128][n][k%128]*weight[k][j]
//                   + sum_{k<128} sn[n][k]*shw[k][j] ) + bias[j]
// ---------------------------------------------------------------------------
constexpr int BM = 64;
constexpr int BK = 32;

__global__ __launch_bounds__(256) void gemm_fused(
    const float* __restrict__ support,  // [RR][NN][D]
    const float* __restrict__ sn,       // [NN][D]   (lives in d_out)
    const float* __restrict__ weight,   // [RR*D][D]
    const float* __restrict__ shw,      // [D][D]
    const float* __restrict__ bias,     // [D]
    float* __restrict__ out) {          // [NN][D]
  __shared__ float As[BM][36];
  __shared__ float Bs[BK][D];

  int tid = threadIdx.x;
  int bm0 = blockIdx.x * BM;
  int tn  = tid & 31;
  int tm  = tid >> 5;

  float acc[8][4];
  #pragma unroll
  for (int i = 0; i < 8; i++)
    #pragma unroll
    for (int j = 0; j < 4; j++) acc[i][j] = 0.f;

  for (int kc = 0; kc < 16; kc++) {
    int k0 = kc * BK;
    const float* Asrc;
    int d0;
    if (k0 < 384) { Asrc = support + (size_t)(k0 >> 7) * NN * D; d0 = k0 & 127; }
    else          { Asrc = sn;                                    d0 = k0 - 384; }
    const float* Bsrc = (k0 < 384) ? (weight + (size_t)k0 * D)
                                   : (shw + (size_t)(k0 - 384) * D);

    #pragma unroll
    for (int t = 0; t < 2; t++) {
      int f   = t * 256 + tid;
      int row = f >> 3;
      int kk4 = (f & 7) * 4;
      int grow = bm0 + row;
      float4 va = make_float4(0.f, 0.f, 0.f, 0.f);
      if (grow < NN) va = *(const float4*)(Asrc + (size_t)grow * D + d0 + kk4);
      *(float4*)&As[row][kk4] = va;
    }
    #pragma unroll
    for (int t = 0; t < 4; t++) {
      int f  = t * 256 + tid;
      int kk = f >> 5;
      int j4 = (f & 31) * 4;
      float4 vb = *(const float4*)(Bsrc + (size_t)kk * D + j4);
      *(float4*)&Bs[kk][j4] = vb;
    }
    __syncthreads();

    #pragma unroll
    for (int k4 = 0; k4 < BK; k4 += 4) {
      float4 b0 = *(const float4*)&Bs[k4 + 0][tn * 4];
      float4 b1 = *(const float4*)&Bs[k4 + 1][tn * 4];
      float4 b2 = *(const float4*)&Bs[k4 + 2][tn * 4];
      float4 b3 = *(const float4*)&Bs[k4 + 3][tn * 4];
      #pragma unroll
      for (int i = 0; i < 8; i++) {
        float4 a = *(const float4*)&As[tm * 8 + i][k4];
        acc[i][0] += a.x * b0.x + a.y * b1.x + a.z * b2.x + a.w * b3.x;
        acc[i][1] += a.x * b0.y + a.y * b1.y + a.z * b2.y + a.w * b3.y;
        acc[i][2] += a.x * b0.z + a.y * b1.z + a.z * b2.z + a.w * b3.z;
        acc[i][3] += a.x * b0.w + a.y * b1.w + a.z * b2.w + a.w * b3.w;
      }
    }
    __syncthreads();
  }

  float4 bv = *(const float4*)&bias[tn * 4];
  #pragma unroll
  for (int i = 0; i < 8; i++) {
    int grow = bm0 + tm * 8 + i;
    if (grow < NN) {
      float4 o;
      o.x = 0.5f * acc[i][0] + bv.x;
      o.y = 0.5f * acc[i][1] + bv.y;
      o.z = 0.5f * acc[i][2] + bv.z;
      o.w = 0.5f * acc[i][3] + bv.w;
      *(float4*)&out[(size_t)grow * D + tn * 4] = o;
    }
  }
}

// ---------------------------------------------------------------------------
extern "C" void kernel_launch(void* const* d_in, const int* in_sizes, int n_in,
                              void* d_out, int out_size, void* d_ws, size_t ws_size,
                              hipStream_t stream) {
  const float* input  = (const float*)d_in[0];
  const int*   arows  = (const int*)  d_in[1];
  const int*   acols  = (const int*)  d_in[2];
  const float* avals  = (const float*)d_in[3];
  const float* weight = (const float*)d_in[4];
  const float* shw    = (const float*)d_in[5];
  const float* bias   = (const float*)d_in[6];
  const float* gamma  = (const float*)d_in[7];
  const float* beta   = (const float*)d_in[8];
  float* out = (float*)d_out;

  // Workspace layout (16B-aligned chunks):
  //   support : RR*NN*D floats          = 76.8 MB
  //   epack   : NE int2                 = 19.2 MB
  //   off     : RN+1 ints
  //   cur     : RN   ints
  //   bsum    : nb   ints
  char* ws = (char*)d_ws;
  float* support = (float*)ws;                 ws += (size_t)RR * NN * D * sizeof(float);
  int2*  epack   = (int2*)ws;                  ws += (size_t)NE * sizeof(int2);
  int*   off     = (int*)ws;                   ws += ((size_t)RN + 4) * sizeof(int);
  int*   cur     = (int*)ws;                   ws += (size_t)RN * sizeof(int);
  int*   bsum    = (int*)ws;

  int nb = (RN + 1023) / 1024;                 // 147 scan blocks
  float* sn = out;                             // LN output parked in d_out

  hipMemsetAsync(cur, 0, (size_t)RN * sizeof(int), stream);
  hist_rows <<<(NE + 255) / 256, 256, 0, stream>>>(arows, cur);
  scan_local<<<nb, 256, 0, stream>>>(cur, off, bsum);
  scan_bsums<<<1, 64, 0, stream>>>(bsum, nb);
  scan_apply<<<nb, 256, 0, stream>>>(off, bsum, cur, nb);
  fill_csr  <<<(NE + 255) / 256, 256, 0, stream>>>(arows, acols, avals, cur, epack);
  gather_ln <<<(NN + 3) / 4, 256, 0, stream>>>(input, epack, off, gamma, beta, support, sn);
  gemm_fused<<<(NN + BM - 1) / BM, 256, 0, stream>>>(support, sn, weight, shw, bias, out);
}

// Round 3
// 658.294 us; speedup vs baseline: 6.4584x; 1.1276x over previous
//
#include <hip/hip_runtime.h>

// Problem constants (fixed by the reference)
constexpr int NN  = 50000;   // nodes
constexpr int NNZ = 800000;  // edges per relation
constexpr int RR  = 3;       // relations
constexpr int D   = 128;     // feature dim (in == out)
constexpr int RN  = RR * NN; // buckets
constexpr int NE  = RR * NNZ;
constexpr float EPS = 1e-6f;

// ---------------------------------------------------------------------------
// K1: histogram of destination rows per relation. cnt[r*NN+row]++
// ---------------------------------------------------------------------------
__global__ __launch_bounds__(256) void hist_rows(
    const int* __restrict__ rows, int* __restrict__ cnt) {
  int e = blockIdx.x * 256 + threadIdx.x;
  if (e >= NE) return;
  int r = (e >= 2 * NNZ) ? 2 : (e >= NNZ ? 1 : 0);
  atomicAdd(&cnt[r * NN + rows[e]], 1);
}

// ---------------------------------------------------------------------------
// K2a: per-block local exclusive scan (1024 elems/block) + block sums
// ---------------------------------------------------------------------------
__global__ __launch_bounds__(256) void scan_local(
    const int* __restrict__ cnt, int* __restrict__ off, int* __restrict__ bsum) {
  __shared__ int sdata[256];
  int t = threadIdx.x;
  int base = blockIdx.x * 1024 + t * 4;
  int c[4];
  #pragma unroll
  for (int j = 0; j < 4; j++) c[j] = (base + j < RN) ? cnt[base + j] : 0;
  int s = c[0] + c[1] + c[2] + c[3];
  sdata[t] = s;
  __syncthreads();
  #pragma unroll
  for (int step = 1; step < 256; step <<= 1) {
    int v = (t >= step) ? sdata[t - step] : 0;
    __syncthreads();
    sdata[t] += v;
    __syncthreads();
  }
  int excl = sdata[t] - s;
  if (base + 0 < RN) off[base + 0] = excl;
  if (base + 1 < RN) off[base + 1] = excl + c[0];
  if (base + 2 < RN) off[base + 2] = excl + c[0] + c[1];
  if (base + 3 < RN) off[base + 3] = excl + c[0] + c[1] + c[2];
  if (t == 255) bsum[blockIdx.x] = sdata[255];
}

// ---------------------------------------------------------------------------
// K2b: inclusive scan of block sums (single wave, shfl scan with carry)
// ---------------------------------------------------------------------------
__global__ __launch_bounds__(64) void scan_bsums(int* __restrict__ bsum, int nb) {
  int l = threadIdx.x;
  int carry = 0;
  for (int base = 0; base < nb; base += 64) {
    int i = base + l;
    int v = (i < nb) ? bsum[i] : 0;
    #pragma unroll
    for (int s = 1; s < 64; s <<= 1) {
      int u = __shfl_up(v, s);
      if (l >= s) v += u;
    }
    int tot = __shfl(v, 63);
    if (i < nb) bsum[i] = v + carry;
    carry += tot;
  }
}

// ---------------------------------------------------------------------------
// K2c: apply block offsets; init cursors; write off[RN] = total
// ---------------------------------------------------------------------------
__global__ __launch_bounds__(256) void scan_apply(
    int* __restrict__ off, const int* __restrict__ bsum, int* __restrict__ cur, int nb) {
  int b = blockIdx.x;
  int add = (b > 0) ? bsum[b - 1] : 0;
  int base = b * 1024 + threadIdx.x * 4;
  #pragma unroll
  for (int j = 0; j < 4; j++) {
    int i = base + j;
    if (i < RN) {
      int v = off[i] + add;
      off[i] = v;
      cur[i] = v;
    }
  }
  if (b == 0 && threadIdx.x == 0) off[RN] = bsum[nb - 1];
}

// ---------------------------------------------------------------------------
// K3: fill sorted (col, val) pairs per bucket
// ---------------------------------------------------------------------------
__global__ __launch_bounds__(256) void fill_csr(
    const int* __restrict__ rows, const int* __restrict__ cols,
    const float* __restrict__ vals, int* __restrict__ cur,
    int2* __restrict__ epack) {
  int e = blockIdx.x * 256 + threadIdx.x;
  if (e >= NE) return;
  int r = (e >= 2 * NNZ) ? 2 : (e >= NNZ ? 1 : 0);
  int b = r * NN + rows[e];
  int pos = atomicAdd(&cur[b], 1);
  epack[pos] = make_int2(cols[e], __float_as_int(vals[e]));
}

// ---------------------------------------------------------------------------
// K4: gather SpMM for all 3 relations + sum + LayerNorm, fused.
// One 64-lane wave per node; each lane owns 2 feature dims (float2).
// Edge loop unrolled x8 with all gathers issued before use -> 8-deep MLP.
// ---------------------------------------------------------------------------
__global__ __launch_bounds__(256) void gather_ln(
    const float* __restrict__ x,       // [NN][D]
    const int2*  __restrict__ epack,   // [NE] sorted by bucket
    const int*   __restrict__ off,     // [RN+1]
    const float* __restrict__ gamma,
    const float* __restrict__ beta,
    float* __restrict__ support,       // [RR][NN][D]
    float* __restrict__ sn) {          // [NN][D]
  int node = blockIdx.x * 4 + (threadIdx.x >> 6);
  if (node >= NN) return;
  int l = threadIdx.x & 63;
  float2 tot = make_float2(0.f, 0.f);
  #pragma unroll
  for (int r = 0; r < RR; r++) {
    int b = r * NN + node;
    int s = off[b], e2 = off[b + 1];
    float2 acc = make_float2(0.f, 0.f);
    int i = s;
    for (; i + 8 <= e2; i += 8) {
      int2 p0 = epack[i + 0];
      int2 p1 = epack[i + 1];
      int2 p2 = epack[i + 2];
      int2 p3 = epack[i + 3];
      int2 p4 = epack[i + 4];
      int2 p5 = epack[i + 5];
      int2 p6 = epack[i + 6];
      int2 p7 = epack[i + 7];
      float2 x0 = ((const float2*)(x + (size_t)p0.x * D))[l];
      float2 x1 = ((const float2*)(x + (size_t)p1.x * D))[l];
      float2 x2 = ((const float2*)(x + (size_t)p2.x * D))[l];
      float2 x3 = ((const float2*)(x + (size_t)p3.x * D))[l];
      float2 x4 = ((const float2*)(x + (size_t)p4.x * D))[l];
      float2 x5 = ((const float2*)(x + (size_t)p5.x * D))[l];
      float2 x6 = ((const float2*)(x + (size_t)p6.x * D))[l];
      float2 x7 = ((const float2*)(x + (size_t)p7.x * D))[l];
      float v0 = __int_as_float(p0.y), v1 = __int_as_float(p1.y);
      float v2 = __int_as_float(p2.y), v3 = __int_as_float(p3.y);
      float v4 = __int_as_float(p4.y), v5 = __int_as_float(p5.y);
      float v6 = __int_as_float(p6.y), v7 = __int_as_float(p7.y);
      acc.x += v0 * x0.x + v1 * x1.x + v2 * x2.x + v3 * x3.x
             + v4 * x4.x + v5 * x5.x + v6 * x6.x + v7 * x7.x;
      acc.y += v0 * x0.y + v1 * x1.y + v2 * x2.y + v3 * x3.y
             + v4 * x4.y + v5 * x5.y + v6 * x6.y + v7 * x7.y;
    }
    for (; i + 2 <= e2; i += 2) {
      int2 p0 = epack[i + 0];
      int2 p1 = epack[i + 1];
      float2 x0 = ((const float2*)(x + (size_t)p0.x * D))[l];
      float2 x1 = ((const float2*)(x + (size_t)p1.x * D))[l];
      acc.x += __int_as_float(p0.y) * x0.x + __int_as_float(p1.y) * x1.x;
      acc.y += __int_as_float(p0.y) * x0.y + __int_as_float(p1.y) * x1.y;
    }
    for (; i < e2; i++) {
      int2 p = epack[i];
      float v = __int_as_float(p.y);
      float2 xv = ((const float2*)(x + (size_t)p.x * D))[l];
      acc.x += v * xv.x;
      acc.y += v * xv.y;
    }
    ((float2*)(support + ((size_t)r * NN + node) * D))[l] = acc;
    tot.x += acc.x;
    tot.y += acc.y;
  }
  float sum = tot.x + tot.y;
  float sq  = tot.x * tot.x + tot.y * tot.y;
  #pragma unroll
  for (int m = 32; m >= 1; m >>= 1) {
    sum += __shfl_xor(sum, m);
    sq  += __shfl_xor(sq,  m);
  }
  float mean = sum * (1.0f / D);
  float var  = sq * (1.0f / D) - mean * mean;
  float rstd = rsqrtf(var + EPS);
  int d = l * 2;
  float o0 = (tot.x - mean) * rstd * gamma[d]     + beta[d];
  float o1 = (tot.y - mean) * rstd * gamma[d + 1] + beta[d + 1];
  ((float2*)(sn + (size_t)node * D))[l] = make_float2(o0, o1);
}

// ---------------------------------------------------------------------------
// K5: fused GEMM.
//   out[n][j] = 0.5*( sum_{k<384} support[k/128][n][k%128]*weight[k][j]
//                   + sum_{k<128} sn[n][k]*shw[k][j] ) + bias[j]
// ---------------------------------------------------------------------------
constexpr int BM = 64;
constexpr int BK = 32;

__global__ __launch_bounds__(256) void gemm_fused(
    const float* __restrict__ support,  // [RR][NN][D]
    const float* __restrict__ sn,       // [NN][D]   (lives in d_out)
    const float* __restrict__ weight,   // [RR*D][D]
    const float* __restrict__ shw,      // [D][D]
    const float* __restrict__ bias,     // [D]
    float* __restrict__ out) {          // [NN][D]
  __shared__ float As[BM][36];
  __shared__ float Bs[BK][D];

  int tid = threadIdx.x;
  int bm0 = blockIdx.x * BM;
  int tn  = tid & 31;
  int tm  = tid >> 5;

  float acc[8][4];
  #pragma unroll
  for (int i = 0; i < 8; i++)
    #pragma unroll
    for (int j = 0; j < 4; j++) acc[i][j] = 0.f;

  for (int kc = 0; kc < 16; kc++) {
    int k0 = kc * BK;
    const float* Asrc;
    int d0;
    if (k0 < 384) { Asrc = support + (size_t)(k0 >> 7) * NN * D; d0 = k0 & 127; }
    else          { Asrc = sn;                                    d0 = k0 - 384; }
    const float* Bsrc = (k0 < 384) ? (weight + (size_t)k0 * D)
                                   : (shw + (size_t)(k0 - 384) * D);

    #pragma unroll
    for (int t = 0; t < 2; t++) {
      int f   = t * 256 + tid;
      int row = f >> 3;
      int kk4 = (f & 7) * 4;
      int grow = bm0 + row;
      float4 va = make_float4(0.f, 0.f, 0.f, 0.f);
      if (grow < NN) va = *(const float4*)(Asrc + (size_t)grow * D + d0 + kk4);
      *(float4*)&As[row][kk4] = va;
    }
    #pragma unroll
    for (int t = 0; t < 4; t++) {
      int f  = t * 256 + tid;
      int kk = f >> 5;
      int j4 = (f & 31) * 4;
      float4 vb = *(const float4*)(Bsrc + (size_t)kk * D + j4);
      *(float4*)&Bs[kk][j4] = vb;
    }
    __syncthreads();

    #pragma unroll
    for (int k4 = 0; k4 < BK; k4 += 4) {
      float4 b0 = *(const float4*)&Bs[k4 + 0][tn * 4];
      float4 b1 = *(const float4*)&Bs[k4 + 1][tn * 4];
      float4 b2 = *(const float4*)&Bs[k4 + 2][tn * 4];
      float4 b3 = *(const float4*)&Bs[k4 + 3][tn * 4];
      #pragma unroll
      for (int i = 0; i < 8; i++) {
        float4 a = *(const float4*)&As[tm * 8 + i][k4];
        acc[i][0] += a.x * b0.x + a.y * b1.x + a.z * b2.x + a.w * b3.x;
        acc[i][1] += a.x * b0.y + a.y * b1.y + a.z * b2.y + a.w * b3.y;
        acc[i][2] += a.x * b0.z + a.y * b1.z + a.z * b2.z + a.w * b3.z;
        acc[i][3] += a.x * b0.w + a.y * b1.w + a.z * b2.w + a.w * b3.w;
      }
    }
    __syncthreads();
  }

  float4 bv = *(const float4*)&bias[tn * 4];
  #pragma unroll
  for (int i = 0; i < 8; i++) {
    int grow = bm0 + tm * 8 + i;
    if (grow < NN) {
      float4 o;
      o.x = 0.5f * acc[i][0] + bv.x;
      o.y = 0.5f * acc[i][1] + bv.y;
      o.z = 0.5f * acc[i][2] + bv.z;
      o.w = 0.5f * acc[i][3] + bv.w;
      *(float4*)&out[(size_t)grow * D + tn * 4] = o;
    }
  }
}

// ---------------------------------------------------------------------------
extern "C" void kernel_launch(void* const* d_in, const int* in_sizes, int n_in,
                              void* d_out, int out_size, void* d_ws, size_t ws_size,
                              hipStream_t stream) {
  const float* input  = (const float*)d_in[0];
  const int*   arows  = (const int*)  d_in[1];
  const int*   acols  = (const int*)  d_in[2];
  const float* avals  = (const float*)d_in[3];
  const float* weight = (const float*)d_in[4];
  const float* shw    = (const float*)d_in[5];
  const float* bias   = (const float*)d_in[6];
  const float* gamma  = (const float*)d_in[7];
  const float* beta   = (const float*)d_in[8];
  float* out = (float*)d_out;

  // Workspace layout:
  //   support : RR*NN*D floats          = 76.8 MB
  //   epack   : NE int2                 = 19.2 MB
  //   off     : RN+1 ints ; cur : RN ints ; bsum : nb ints
  char* ws = (char*)d_ws;
  float* support = (float*)ws;                 ws += (size_t)RR * NN * D * sizeof(float);
  int2*  epack   = (int2*)ws;                  ws += (size_t)NE * sizeof(int2);
  int*   off     = (int*)ws;                   ws += ((size_t)RN + 4) * sizeof(int);
  int*   cur     = (int*)ws;                   ws += (size_t)RN * sizeof(int);
  int*   bsum    = (int*)ws;

  int nb = (RN + 1023) / 1024;                 // 147 scan blocks
  float* sn = out;                             // LN output parked in d_out

  hipMemsetAsync(cur, 0, (size_t)RN * sizeof(int), stream);
  hist_rows <<<(NE + 255) / 256, 256, 0, stream>>>(arows, cur);
  scan_local<<<nb, 256, 0, stream>>>(cur, off, bsum);
  scan_bsums<<<1, 64, 0, stream>>>(bsum, nb);
  scan_apply<<<nb, 256, 0, stream>>>(off, bsum, cur, nb);
  fill_csr  <<<(NE + 255) / 256, 256, 0, stream>>>(arows, acols, avals, cur, epack);
  gather_ln <<<(NN + 3) / 4, 256, 0, stream>>>(input, epack, off, gamma, beta, support, sn);
  gemm_fused<<<(NN + BM - 1) / BM, 256, 0, stream>>>(support, sn, weight, shw, bias, out);
}

// Round 4
// 466.405 us; speedup vs baseline: 9.1155x; 1.4114x over previous
//
#include <hip/hip_runtime.h>

// Problem constants (fixed by the reference)
constexpr int NN  = 50000;   // nodes
constexpr int NNZ = 800000;  // edges per relation
constexpr int RR  = 3;       // relations
constexpr int D   = 128;     // feature dim (in == out)
constexpr int RN  = RR * NN; // buckets
constexpr int NE  = RR * NNZ;
constexpr int KK  = 512;     // concat K: 3*128 support + 128 layernorm
constexpr int MPAD = 50048;  // 782 * 64, padded row count for A
constexpr float EPS = 1e-6f;

using bf16x8 = __attribute__((ext_vector_type(8))) __bf16;
using f32x4  = __attribute__((ext_vector_type(4))) float;

// RNE f32 -> bf16 (bit-exact round-to-nearest-even; NaN not possible here)
__device__ __forceinline__ unsigned pack_bf2(float a, float b) {
  unsigned ua = __float_as_uint(a); ua = (ua + (0x7FFFu + ((ua >> 16) & 1))) >> 16;
  unsigned ub = __float_as_uint(b); ub = (ub + (0x7FFFu + ((ub >> 16) & 1))) >> 16;
  return ua | (ub << 16);
}

__device__ __forceinline__ void gload16(const void* g, void* l) {
  __builtin_amdgcn_global_load_lds(
      (const __attribute__((address_space(1))) unsigned int*)g,
      (__attribute__((address_space(3))) unsigned int*)l, 16, 0, 0);
}

// ---------------------------------------------------------------------------
// K1: histogram of destination rows per relation. cnt[r*NN+row]++
// ---------------------------------------------------------------------------
__global__ __launch_bounds__(256) void hist_rows(
    const int* __restrict__ rows, int* __restrict__ cnt) {
  int e = blockIdx.x * 256 + threadIdx.x;
  if (e >= NE) return;
  int r = (e >= 2 * NNZ) ? 2 : (e >= NNZ ? 1 : 0);
  atomicAdd(&cnt[r * NN + rows[e]], 1);
}

// ---------------------------------------------------------------------------
// K2a/b/c: hierarchical exclusive scan of 150k counts
// ---------------------------------------------------------------------------
__global__ __launch_bounds__(256) void scan_local(
    const int* __restrict__ cnt, int* __restrict__ off, int* __restrict__ bsum) {
  __shared__ int sdata[256];
  int t = threadIdx.x;
  int base = blockIdx.x * 1024 + t * 4;
  int c[4];
  #pragma unroll
  for (int j = 0; j < 4; j++) c[j] = (base + j < RN) ? cnt[base + j] : 0;
  int s = c[0] + c[1] + c[2] + c[3];
  sdata[t] = s;
  __syncthreads();
  #pragma unroll
  for (int step = 1; step < 256; step <<= 1) {
    int v = (t >= step) ? sdata[t - step] : 0;
    __syncthreads();
    sdata[t] += v;
    __syncthreads();
  }
  int excl = sdata[t] - s;
  if (base + 0 < RN) off[base + 0] = excl;
  if (base + 1 < RN) off[base + 1] = excl + c[0];
  if (base + 2 < RN) off[base + 2] = excl + c[0] + c[1];
  if (base + 3 < RN) off[base + 3] = excl + c[0] + c[1] + c[2];
  if (t == 255) bsum[blockIdx.x] = sdata[255];
}

__global__ __launch_bounds__(64) void scan_bsums(int* __restrict__ bsum, int nb) {
  int l = threadIdx.x;
  int carry = 0;
  for (int base = 0; base < nb; base += 64) {
    int i = base + l;
    int v = (i < nb) ? bsum[i] : 0;
    #pragma unroll
    for (int s = 1; s < 64; s <<= 1) {
      int u = __shfl_up(v, s);
      if (l >= s) v += u;
    }
    int tot = __shfl(v, 63);
    if (i < nb) bsum[i] = v + carry;
    carry += tot;
  }
}

__global__ __launch_bounds__(256) void scan_apply(
    int* __restrict__ off, const int* __restrict__ bsum, int* __restrict__ cur, int nb) {
  int b = blockIdx.x;
  int add = (b > 0) ? bsum[b - 1] : 0;
  int base = b * 1024 + threadIdx.x * 4;
  #pragma unroll
  for (int j = 0; j < 4; j++) {
    int i = base + j;
    if (i < RN) {
      int v = off[i] + add;
      off[i] = v;
      cur[i] = v;
    }
  }
  if (b == 0 && threadIdx.x == 0) off[RN] = bsum[nb - 1];
}

// ---------------------------------------------------------------------------
// K3: fill sorted (col, val) pairs per bucket
// ---------------------------------------------------------------------------
__global__ __launch_bounds__(256) void fill_csr(
    const int* __restrict__ rows, const int* __restrict__ cols,
    const float* __restrict__ vals, int* __restrict__ cur,
    int2* __restrict__ epack) {
  int e = blockIdx.x * 256 + threadIdx.x;
  if (e >= NE) return;
  int r = (e >= 2 * NNZ) ? 2 : (e >= NNZ ? 1 : 0);
  int b = r * NN + rows[e];
  int pos = atomicAdd(&cur[b], 1);
  epack[pos] = make_int2(cols[e], __float_as_int(vals[e]));
}

// ---------------------------------------------------------------------------
// K4: gather SpMM (3 relations) + sum + LayerNorm, fused.
// One wave per node; lane owns dims {2l, 2l+1}. Emits the concatenated
// GEMM A-matrix row in bf16: A[node][0..383]=support slabs, [384..511]=LN.
// ---------------------------------------------------------------------------
__global__ __launch_bounds__(256) void gather_ln(
    const float* __restrict__ x,       // [NN][D]
    const int2*  __restrict__ epack,   // [NE] sorted by bucket
    const int*   __restrict__ off,     // [RN+1]
    const float* __restrict__ gamma,
    const float* __restrict__ beta,
    unsigned* __restrict__ Au) {       // A as uint view: [MPAD][256]
  int node = blockIdx.x * 4 + (threadIdx.x >> 6);
  if (node >= NN) return;
  int l = threadIdx.x & 63;
  float2 tot = make_float2(0.f, 0.f);
  #pragma unroll
  for (int r = 0; r < RR; r++) {
    int b = r * NN + node;
    int s = off[b], e2 = off[b + 1];
    float2 acc = make_float2(0.f, 0.f);
    int i = s;
    for (; i + 8 <= e2; i += 8) {
      int2 p0 = epack[i + 0];
      int2 p1 = epack[i + 1];
      int2 p2 = epack[i + 2];
      int2 p3 = epack[i + 3];
      int2 p4 = epack[i + 4];
      int2 p5 = epack[i + 5];
      int2 p6 = epack[i + 6];
      int2 p7 = epack[i + 7];
      float2 x0 = ((const float2*)(x + (size_t)p0.x * D))[l];
      float2 x1 = ((const float2*)(x + (size_t)p1.x * D))[l];
      float2 x2 = ((const float2*)(x + (size_t)p2.x * D))[l];
      float2 x3 = ((const float2*)(x + (size_t)p3.x * D))[l];
      float2 x4 = ((const float2*)(x + (size_t)p4.x * D))[l];
      float2 x5 = ((const float2*)(x + (size_t)p5.x * D))[l];
      float2 x6 = ((const float2*)(x + (size_t)p6.x * D))[l];
      float2 x7 = ((const float2*)(x + (size_t)p7.x * D))[l];
      float v0 = __int_as_float(p0.y), v1 = __int_as_float(p1.y);
      float v2 = __int_as_float(p2.y), v3 = __int_as_float(p3.y);
      float v4 = __int_as_float(p4.y), v5 = __int_as_float(p5.y);
      float v6 = __int_as_float(p6.y), v7 = __int_as_float(p7.y);
      acc.x += v0 * x0.x + v1 * x1.x + v2 * x2.x + v3 * x3.x
             + v4 * x4.x + v5 * x5.x + v6 * x6.x + v7 * x7.x;
      acc.y += v0 * x0.y + v1 * x1.y + v2 * x2.y + v3 * x3.y
             + v4 * x4.y + v5 * x5.y + v6 * x6.y + v7 * x7.y;
    }
    for (; i + 2 <= e2; i += 2) {
      int2 p0 = epack[i + 0];
      int2 p1 = epack[i + 1];
      float2 x0 = ((const float2*)(x + (size_t)p0.x * D))[l];
      float2 x1 = ((const float2*)(x + (size_t)p1.x * D))[l];
      acc.x += __int_as_float(p0.y) * x0.x + __int_as_float(p1.y) * x1.x;
      acc.y += __int_as_float(p0.y) * x0.y + __int_as_float(p1.y) * x1.y;
    }
    for (; i < e2; i++) {
      int2 p = epack[i];
      float v = __int_as_float(p.y);
      float2 xv = ((const float2*)(x + (size_t)p.x * D))[l];
      acc.x += v * xv.x;
      acc.y += v * xv.y;
    }
    Au[(size_t)node * 256 + r * 64 + l] = pack_bf2(acc.x, acc.y);
    tot.x += acc.x;
    tot.y += acc.y;
  }
  float sum = tot.x + tot.y;
  float sq  = tot.x * tot.x + tot.y * tot.y;
  #pragma unroll
  for (int m = 32; m >= 1; m >>= 1) {
    sum += __shfl_xor(sum, m);
    sq  += __shfl_xor(sq,  m);
  }
  float mean = sum * (1.0f / D);
  float var  = sq * (1.0f / D) - mean * mean;
  float rstd = rsqrtf(var + EPS);
  int d = l * 2;
  float o0 = (tot.x - mean) * rstd * gamma[d]     + beta[d];
  float o1 = (tot.y - mean) * rstd * gamma[d + 1] + beta[d + 1];
  Au[(size_t)node * 256 + 192 + l] = pack_bf2(o0, o1);
}

// ---------------------------------------------------------------------------
// K4b: build W^T bf16 [128 cols][512 k]: k<384 from weight, else share_weight
// ---------------------------------------------------------------------------
__global__ __launch_bounds__(256) void build_wt(
    const float* __restrict__ w,    // [384][128]
    const float* __restrict__ shw,  // [128][128]
    unsigned short* __restrict__ WT) { // bf16 [128][512]
  int idx = blockIdx.x * 256 + threadIdx.x;  // 65536
  int k   = idx >> 7;
  int col = idx & 127;
  float v = (k < 384) ? w[k * 128 + col] : shw[(k - 384) * 128 + col];
  unsigned u = __float_as_uint(v);
  WT[col * 512 + k] = (unsigned short)((u + (0x7FFFu + ((u >> 16) & 1))) >> 16);
}

// ---------------------------------------------------------------------------
// K5: bf16 MFMA GEMM.  out = 0.5 * A[50000][512] @ W[512][128] + bias
// BM=64, BN=128 (full), BK=64. 4 waves (2x2), each wave 32 rows x 64 cols.
// global_load_lds staging, XOR-swizzled source slots (rule #21), swizzled
// ds_read_b128 fragment loads; mfma_f32_16x16x32_bf16 (m92-verified layout).
// ---------------------------------------------------------------------------
__global__ __launch_bounds__(256) void gemm_mfma(
    const char* __restrict__ Ab,    // bf16 [MPAD][512] as bytes
    const char* __restrict__ Bb,    // bf16 [128][512] (W^T) as bytes
    const float* __restrict__ bias, // [128]
    float* __restrict__ out) {      // [NN][128]
  __shared__ __align__(16) char smem[24576];   // As 8KB | Bs 16KB
  char* As = smem;
  char* Bs = smem + 8192;

  int tid  = threadIdx.x;
  int wid  = tid >> 6;
  int lane = tid & 63;
  int wr   = wid >> 1;       // wave row (0..1): rows wr*32..wr*32+31
  int wc   = wid & 1;        // wave col (0..1): cols wc*64..wc*64+63
  int row0 = blockIdx.x * 64;

  f32x4 zero = {0.f, 0.f, 0.f, 0.f};
  f32x4 acc[2][4];
  #pragma unroll
  for (int i = 0; i < 2; i++)
    #pragma unroll
    for (int j = 0; j < 4; j++) acc[i][j] = zero;

  for (int kc = 0; kc < 8; kc++) {
    // stage A tile: 64 rows x 128B; 512 chunks of 16B; 2 per thread
    #pragma unroll
    for (int i = 0; i < 2; i++) {
      int c = i * 256 + tid;
      int r = c >> 3, s = c & 7;
      int ss = s ^ (r & 7);
      const void* src = Ab + (size_t)(row0 + r) * 1024 + kc * 128 + ss * 16;
      void* dst = As + i * 4096 + wid * 1024;   // wave-uniform base
      gload16(src, dst);
    }
    // stage B tile: 128 rows(cols of W) x 128B; 1024 chunks; 4 per thread
    #pragma unroll
    for (int i = 0; i < 4; i++) {
      int c = i * 256 + tid;
      int r = c >> 3, s = c & 7;
      int ss = s ^ (r & 7);
      const void* src = Bb + (size_t)r * 1024 + kc * 128 + ss * 16;
      void* dst = Bs + i * 4096 + wid * 1024;
      gload16(src, dst);
    }
    __syncthreads();

    #pragma unroll
    for (int ks = 0; ks < 2; ks++) {
      bf16x8 afrag[2], bfrag[4];
      int sg = ks * 4 + (lane >> 4);           // global 16B slot in the 128B row
      #pragma unroll
      for (int rb = 0; rb < 2; rb++) {
        int r = wr * 32 + rb * 16 + (lane & 15);
        afrag[rb] = *(const bf16x8*)(As + r * 128 + (sg ^ (r & 7)) * 16);
      }
      #pragma unroll
      for (int cb = 0; cb < 4; cb++) {
        int col = wc * 64 + cb * 16 + (lane & 15);
        bfrag[cb] = *(const bf16x8*)(Bs + col * 128 + (sg ^ (col & 7)) * 16);
      }
      #pragma unroll
      for (int rb = 0; rb < 2; rb++)
        #pragma unroll
        for (int cb = 0; cb < 4; cb++)
          acc[rb][cb] = __builtin_amdgcn_mfma_f32_16x16x32_bf16(
              afrag[rb], bfrag[cb], acc[rb][cb], 0, 0, 0);
    }
    __syncthreads();
  }

  // epilogue: out = 0.5*acc + bias ; C/D layout col=lane&15, row=(lane>>4)*4+r
  #pragma unroll
  for (int rb = 0; rb < 2; rb++) {
    #pragma unroll
    for (int cb = 0; cb < 4; cb++) {
      int col = wc * 64 + cb * 16 + (lane & 15);
      float bv = bias[col];
      #pragma unroll
      for (int r = 0; r < 4; r++) {
        int grow = row0 + wr * 32 + rb * 16 + (lane >> 4) * 4 + r;
        if (grow < NN) out[(size_t)grow * 128 + col] = 0.5f * acc[rb][cb][r] + bv;
      }
    }
  }
}

// ---------------------------------------------------------------------------
extern "C" void kernel_launch(void* const* d_in, const int* in_sizes, int n_in,
                              void* d_out, int out_size, void* d_ws, size_t ws_size,
                              hipStream_t stream) {
  const float* input  = (const float*)d_in[0];
  const int*   arows  = (const int*)  d_in[1];
  const int*   acols  = (const int*)  d_in[2];
  const float* avals  = (const float*)d_in[3];
  const float* weight = (const float*)d_in[4];
  const float* shw    = (const float*)d_in[5];
  const float* bias   = (const float*)d_in[6];
  const float* gamma  = (const float*)d_in[7];
  const float* beta   = (const float*)d_in[8];
  float* out = (float*)d_out;

  // Workspace layout:
  //   A     : MPAD*512 bf16 = 51.25 MB (concat support slabs + LN slab)
  //   WT    : 128*512 bf16  = 128 KB
  //   epack : NE int2       = 19.2 MB
  //   off/cur/bsum : small
  char* ws = (char*)d_ws;
  char*  Abf  = ws;                          ws += (size_t)MPAD * KK * 2;
  unsigned short* WT = (unsigned short*)ws;  ws += (size_t)128 * KK * 2;
  int2*  epack = (int2*)ws;                  ws += (size_t)NE * sizeof(int2);
  int*   off   = (int*)ws;                   ws += ((size_t)RN + 4) * sizeof(int);
  int*   cur   = (int*)ws;                   ws += (size_t)RN * sizeof(int);
  int*   bsum  = (int*)ws;

  int nb = (RN + 1023) / 1024;               // 147 scan blocks

  hipMemsetAsync(cur, 0, (size_t)RN * sizeof(int), stream);
  build_wt  <<<256, 256, 0, stream>>>(weight, shw, WT);
  hist_rows <<<(NE + 255) / 256, 256, 0, stream>>>(arows, cur);
  scan_local<<<nb, 256, 0, stream>>>(cur, off, bsum);
  scan_bsums<<<1, 64, 0, stream>>>(bsum, nb);
  scan_apply<<<nb, 256, 0, stream>>>(off, bsum, cur, nb);
  fill_csr  <<<(NE + 255) / 256, 256, 0, stream>>>(arows, acols, avals, cur, epack);
  gather_ln <<<(NN + 3) / 4, 256, 0, stream>>>(input, epack, off, gamma, beta,
                                               (unsigned*)Abf);
  gemm_mfma <<<MPAD / 64, 256, 0, stream>>>(Abf, (const char*)WT, bias, out);
}

// Round 5
// 356.258 us; speedup vs baseline: 11.9339x; 1.3092x over previous
//
#include <hip/hip_runtime.h>

// Problem constants (fixed by the reference)
constexpr int NN  = 50000;   // nodes
constexpr int NNZ = 800000;  // edges per relation
constexpr int RR  = 3;       // relations
constexpr int D   = 128;     // feature dim (in == out)
constexpr int RN  = RR * NN; // fine buckets (150000)
constexpr int NE  = RR * NNZ;
constexpr int KK  = 512;     // concat K: 3*128 support + 128 layernorm
constexpr int MPAD = 50048;  // 782 * 64, padded row count for A
constexpr int PART = 16;     // coarse partitions (XCD-local scatter)
constexpr int PSZ  = RN / PART;   // 9375 buckets per partition (exact)
constexpr int CAP  = 160000; // partition capacity (mean 150k, sigma ~375)
constexpr float EPS = 1e-6f;

using bf16x8 = __attribute__((ext_vector_type(8))) __bf16;
using f32x4  = __attribute__((ext_vector_type(4))) float;

// RNE f32 -> bf16 packing helpers (NaN not possible here)
__device__ __forceinline__ unsigned pack_bf2(float a, float b) {
  unsigned ua = __float_as_uint(a); ua = (ua + (0x7FFFu + ((ua >> 16) & 1))) >> 16;
  unsigned ub = __float_as_uint(b); ub = (ub + (0x7FFFu + ((ub >> 16) & 1))) >> 16;
  return ua | (ub << 16);
}
__device__ __forceinline__ unsigned bf16_lo(float a) {
  unsigned ua = __float_as_uint(a);
  return (ua + (0x7FFFu + ((ua >> 16) & 1))) >> 16;
}

__device__ __forceinline__ void gload16(const void* g, void* l) {
  __builtin_amdgcn_global_load_lds(
      (const __attribute__((address_space(1))) unsigned int*)g,
      (__attribute__((address_space(3))) unsigned int*)l, 16, 0, 0);
}

// ---------------------------------------------------------------------------
// K1: multisplit. Edges -> 16 coarse partitions (by fine-bucket range) with
// LDS ranking (1 LDS atomic/edge, 16 global atomics/block). Also fuses the
// fine-bucket histogram (cnt[bucket]++). Payload: {bucket, col16|bf16(val)}.
// ---------------------------------------------------------------------------
__global__ __launch_bounds__(256) void part_split(
    const int*   __restrict__ rows,
    const int*   __restrict__ cols,
    const float* __restrict__ vals,
    int* __restrict__ cnt,       // [RN] fine histogram
    int* __restrict__ pcur,      // [PART]
    uint2* __restrict__ pedges) { // [PART*CAP]
  __shared__ int lcur[PART], lbase[PART];
  int t = threadIdx.x;
  if (t < PART) lcur[t] = 0;
  __syncthreads();
  int e0 = blockIdx.x * 1024;
  int bkt[4], pe[4], rank[4];
  unsigned pay[4];
  #pragma unroll
  for (int j = 0; j < 4; j++) {
    int e = e0 + j * 256 + t;
    if (e < NE) {
      int r = (e >= 2 * NNZ) ? 2 : (e >= NNZ ? 1 : 0);
      int b = r * NN + rows[e];
      bkt[j] = b;
      pe[j]  = b / PSZ;                       // magic-mul div by 9375
      pay[j] = ((unsigned)cols[e] << 16) | bf16_lo(vals[e]);
      rank[j] = atomicAdd(&lcur[pe[j]], 1);
      atomicAdd(&cnt[b], 1);                  // fused histogram
    } else {
      bkt[j] = -1;
    }
  }
  __syncthreads();
  if (t < PART) lbase[t] = atomicAdd(&pcur[t], lcur[t]);
  __syncthreads();
  #pragma unroll
  for (int j = 0; j < 4; j++) {
    if (bkt[j] >= 0) {
      int dst = pe[j] * CAP + lbase[pe[j]] + rank[j];
      pedges[dst] = make_uint2((unsigned)bkt[j], pay[j]);
    }
  }
}

// ---------------------------------------------------------------------------
// K2a/b/c: hierarchical exclusive scan of the 150k fine counts
// ---------------------------------------------------------------------------
__global__ __launch_bounds__(256) void scan_local(
    const int* __restrict__ cnt, int* __restrict__ off, int* __restrict__ bsum) {
  __shared__ int sdata[256];
  int t = threadIdx.x;
  int base = blockIdx.x * 1024 + t * 4;
  int c[4];
  #pragma unroll
  for (int j = 0; j < 4; j++) c[j] = (base + j < RN) ? cnt[base + j] : 0;
  int s = c[0] + c[1] + c[2] + c[3];
  sdata[t] = s;
  __syncthreads();
  #pragma unroll
  for (int step = 1; step < 256; step <<= 1) {
    int v = (t >= step) ? sdata[t - step] : 0;
    __syncthreads();
    sdata[t] += v;
    __syncthreads();
  }
  int excl = sdata[t] - s;
  if (base + 0 < RN) off[base + 0] = excl;
  if (base + 1 < RN) off[base + 1] = excl + c[0];
  if (base + 2 < RN) off[base + 2] = excl + c[0] + c[1];
  if (base + 3 < RN) off[base + 3] = excl + c[0] + c[1] + c[2];
  if (t == 255) bsum[blockIdx.x] = sdata[255];
}

__global__ __launch_bounds__(64) void scan_bsums(int* __restrict__ bsum, int nb) {
  int l = threadIdx.x;
  int carry = 0;
  for (int base = 0; base < nb; base += 64) {
    int i = base + l;
    int v = (i < nb) ? bsum[i] : 0;
    #pragma unroll
    for (int s = 1; s < 64; s <<= 1) {
      int u = __shfl_up(v, s);
      if (l >= s) v += u;
    }
    int tot = __shfl(v, 63);
    if (i < nb) bsum[i] = v + carry;
    carry += tot;
  }
}

__global__ __launch_bounds__(256) void scan_apply(
    int* __restrict__ off, const int* __restrict__ bsum, int* __restrict__ cur, int nb) {
  int b = blockIdx.x;
  int add = (b > 0) ? bsum[b - 1] : 0;
  int base = b * 1024 + threadIdx.x * 4;
  #pragma unroll
  for (int j = 0; j < 4; j++) {
    int i = base + j;
    if (i < RN) {
      int v = off[i] + add;
      off[i] = v;
      cur[i] = v;
    }
  }
  if (b == 0 && threadIdx.x == 0) off[RN] = bsum[nb - 1];
}

// ---------------------------------------------------------------------------
// K3: XCD-local scatter. blockIdx%16 == partition; its epack region (~600KB)
// and cursors (~37.5KB) stay in one XCD's L2 -> single writeback per line.
// ---------------------------------------------------------------------------
__global__ __launch_bounds__(256) void part_scatter(
    const uint2* __restrict__ pedges,
    const int*   __restrict__ pcur,
    int* __restrict__ cur,
    unsigned* __restrict__ epack) {
  int p = blockIdx.x & 15;
  int n = pcur[p];
  const uint2* src = pedges + (size_t)p * CAP;
  int stride = (gridDim.x >> 4) * 256;
  for (int i = (blockIdx.x >> 4) * 256 + threadIdx.x; i < n; i += stride) {
    uint2 ed = src[i];
    int pos = atomicAdd(&cur[ed.x], 1);
    epack[pos] = ed.y;
  }
}

// ---------------------------------------------------------------------------
// K4pre: x -> bf16 pairs. xb[node*64 + l] = bf16x2(x[node][2l], x[node][2l+1])
// ---------------------------------------------------------------------------
__global__ __launch_bounds__(256) void build_xb(
    const float* __restrict__ x, unsigned* __restrict__ xb) {
  int i = blockIdx.x * 256 + threadIdx.x;
  if (i >= NN * 64) return;
  float2 v = ((const float2*)x)[i];
  xb[i] = pack_bf2(v.x, v.y);
}

// ---------------------------------------------------------------------------
// K4: gather SpMM (3 relations) + sum + LayerNorm, fused. bf16 x, 4B epack.
// One wave per node; lane owns dims {2l, 2l+1}. Emits bf16 A row
// [0..383]=support slabs, [384..511]=LN.
// ---------------------------------------------------------------------------
__global__ __launch_bounds__(256) void gather_ln(
    const unsigned* __restrict__ xb,    // [NN][64] bf16x2
    const unsigned* __restrict__ epack, // [NE] col16|bf16val, bucket-sorted
    const int*      __restrict__ off,   // [RN+1]
    const float* __restrict__ gamma,
    const float* __restrict__ beta,
    unsigned* __restrict__ Au) {        // A as uint view: [MPAD][256]
  int node = blockIdx.x * 4 + (threadIdx.x >> 6);
  if (node >= NN) return;
  int l = threadIdx.x & 63;
  float2 tot = make_float2(0.f, 0.f);
  #pragma unroll
  for (int r = 0; r < RR; r++) {
    int b = r * NN + node;
    int s = off[b], e2 = off[b + 1];
    float2 acc = make_float2(0.f, 0.f);
    int i = s;
    for (; i + 8 <= e2; i += 8) {
      unsigned u0 = epack[i + 0], u1 = epack[i + 1];
      unsigned u2 = epack[i + 2], u3 = epack[i + 3];
      unsigned u4 = epack[i + 4], u5 = epack[i + 5];
      unsigned u6 = epack[i + 6], u7 = epack[i + 7];
      unsigned g0 = xb[(u0 >> 16) * 64 + l];
      unsigned g1 = xb[(u1 >> 16) * 64 + l];
      unsigned g2 = xb[(u2 >> 16) * 64 + l];
      unsigned g3 = xb[(u3 >> 16) * 64 + l];
      unsigned g4 = xb[(u4 >> 16) * 64 + l];
      unsigned g5 = xb[(u5 >> 16) * 64 + l];
      unsigned g6 = xb[(u6 >> 16) * 64 + l];
      unsigned g7 = xb[(u7 >> 16) * 64 + l];
      float v0 = __uint_as_float(u0 << 16), v1 = __uint_as_float(u1 << 16);
      float v2 = __uint_as_float(u2 << 16), v3 = __uint_as_float(u3 << 16);
      float v4 = __uint_as_float(u4 << 16), v5 = __uint_as_float(u5 << 16);
      float v6 = __uint_as_float(u6 << 16), v7 = __uint_as_float(u7 << 16);
      acc.x += v0 * __uint_as_float(g0 << 16) + v1 * __uint_as_float(g1 << 16)
             + v2 * __uint_as_float(g2 << 16) + v3 * __uint_as_float(g3 << 16)
             + v4 * __uint_as_float(g4 << 16) + v5 * __uint_as_float(g5 << 16)
             + v6 * __uint_as_float(g6 << 16) + v7 * __uint_as_float(g7 << 16);
      acc.y += v0 * __uint_as_float(g0 & 0xFFFF0000u) + v1 * __uint_as_float(g1 & 0xFFFF0000u)
             + v2 * __uint_as_float(g2 & 0xFFFF0000u) + v3 * __uint_as_float(g3 & 0xFFFF0000u)
             + v4 * __uint_as_float(g4 & 0xFFFF0000u) + v5 * __uint_as_float(g5 & 0xFFFF0000u)
             + v6 * __uint_as_float(g6 & 0xFFFF0000u) + v7 * __uint_as_float(g7 & 0xFFFF0000u);
    }
    for (; i < e2; i++) {
      unsigned u = epack[i];
      unsigned g = xb[(u >> 16) * 64 + l];
      float v = __uint_as_float(u << 16);
      acc.x += v * __uint_as_float(g << 16);
      acc.y += v * __uint_as_float(g & 0xFFFF0000u);
    }
    Au[(size_t)node * 256 + r * 64 + l] = pack_bf2(acc.x, acc.y);
    tot.x += acc.x;
    tot.y += acc.y;
  }
  float sum = tot.x + tot.y;
  float sq  = tot.x * tot.x + tot.y * tot.y;
  #pragma unroll
  for (int m = 32; m >= 1; m >>= 1) {
    sum += __shfl_xor(sum, m);
    sq  += __shfl_xor(sq,  m);
  }
  float mean = sum * (1.0f / D);
  float var  = sq * (1.0f / D) - mean * mean;
  float rstd = rsqrtf(var + EPS);
  int d = l * 2;
  float o0 = (tot.x - mean) * rstd * gamma[d]     + beta[d];
  float o1 = (tot.y - mean) * rstd * gamma[d + 1] + beta[d + 1];
  Au[(size_t)node * 256 + 192 + l] = pack_bf2(o0, o1);
}

// ---------------------------------------------------------------------------
// K4b: build W^T bf16 [128 cols][512 k]: k<384 from weight, else share_weight
// ---------------------------------------------------------------------------
__global__ __launch_bounds__(256) void build_wt(
    const float* __restrict__ w,    // [384][128]
    const float* __restrict__ shw,  // [128][128]
    unsigned short* __restrict__ WT) { // bf16 [128][512]
  int idx = blockIdx.x * 256 + threadIdx.x;  // 65536
  int k   = idx >> 7;
  int col = idx & 127;
  float v = (k < 384) ? w[k * 128 + col] : shw[(k - 384) * 128 + col];
  WT[col * 512 + k] = (unsigned short)bf16_lo(v);
}

// ---------------------------------------------------------------------------
// K5: bf16 MFMA GEMM.  out = 0.5 * A[50000][512] @ W[512][128] + bias
// BM=64, BN=128 (full), BK=64. 4 waves (2x2), each wave 32 rows x 64 cols.
// ---------------------------------------------------------------------------
__global__ __launch_bounds__(256) void gemm_mfma(
    const char* __restrict__ Ab,    // bf16 [MPAD][512] as bytes
    const char* __restrict__ Bb,    // bf16 [128][512] (W^T) as bytes
    const float* __restrict__ bias, // [128]
    float* __restrict__ out) {      // [NN][128]
  __shared__ __align__(16) char smem[24576];   // As 8KB | Bs 16KB
  char* As = smem;
  char* Bs = smem + 8192;

  int tid  = threadIdx.x;
  int wid  = tid >> 6;
  int lane = tid & 63;
  int wr   = wid >> 1;
  int wc   = wid & 1;
  int row0 = blockIdx.x * 64;

  f32x4 zero = {0.f, 0.f, 0.f, 0.f};
  f32x4 acc[2][4];
  #pragma unroll
  for (int i = 0; i < 2; i++)
    #pragma unroll
    for (int j = 0; j < 4; j++) acc[i][j] = zero;

  for (int kc = 0; kc < 8; kc++) {
    #pragma unroll
    for (int i = 0; i < 2; i++) {
      int c = i * 256 + tid;
      int r = c >> 3, s = c & 7;
      int ss = s ^ (r & 7);
      const void* src = Ab + (size_t)(row0 + r) * 1024 + kc * 128 + ss * 16;
      void* dst = As + i * 4096 + wid * 1024;
      gload16(src, dst);
    }
    #pragma unroll
    for (int i = 0; i < 4; i++) {
      int c = i * 256 + tid;
      int r = c >> 3, s = c & 7;
      int ss = s ^ (r & 7);
      const void* src = Bb + (size_t)r * 1024 + kc * 128 + ss * 16;
      void* dst = Bs + i * 4096 + wid * 1024;
      gload16(src, dst);
    }
    __syncthreads();

    #pragma unroll
    for (int ks = 0; ks < 2; ks++) {
      bf16x8 afrag[2], bfrag[4];
      int sg = ks * 4 + (lane >> 4);
      #pragma unroll
      for (int rb = 0; rb < 2; rb++) {
        int r = wr * 32 + rb * 16 + (lane & 15);
        afrag[rb] = *(const bf16x8*)(As + r * 128 + (sg ^ (r & 7)) * 16);
      }
      #pragma unroll
      for (int cb = 0; cb < 4; cb++) {
        int col = wc * 64 + cb * 16 + (lane & 15);
        bfrag[cb] = *(const bf16x8*)(Bs + col * 128 + (sg ^ (col & 7)) * 16);
      }
      #pragma unroll
      for (int rb = 0; rb < 2; rb++)
        #pragma unroll
        for (int cb = 0; cb < 4; cb++)
          acc[rb][cb] = __builtin_amdgcn_mfma_f32_16x16x32_bf16(
              afrag[rb], bfrag[cb], acc[rb][cb], 0, 0, 0);
    }
    __syncthreads();
  }

  #pragma unroll
  for (int rb = 0; rb < 2; rb++) {
    #pragma unroll
    for (int cb = 0; cb < 4; cb++) {
      int col = wc * 64 + cb * 16 + (lane & 15);
      float bv = bias[col];
      #pragma unroll
      for (int r = 0; r < 4; r++) {
        int grow = row0 + wr * 32 + rb * 16 + (lane >> 4) * 4 + r;
        if (grow < NN) out[(size_t)grow * 128 + col] = 0.5f * acc[rb][cb][r] + bv;
      }
    }
  }
}

// ---------------------------------------------------------------------------
extern "C" void kernel_launch(void* const* d_in, const int* in_sizes, int n_in,
                              void* d_out, int out_size, void* d_ws, size_t ws_size,
                              hipStream_t stream) {
  const float* input  = (const float*)d_in[0];
  const int*   arows  = (const int*)  d_in[1];
  const int*   acols  = (const int*)  d_in[2];
  const float* avals  = (const float*)d_in[3];
  const float* weight = (const float*)d_in[4];
  const float* shw    = (const float*)d_in[5];
  const float* bias   = (const float*)d_in[6];
  const float* gamma  = (const float*)d_in[7];
  const float* beta   = (const float*)d_in[8];
  float* out = (float*)d_out;

  // Workspace layout (~95.5 MB):
  //   A      : MPAD*512 bf16      = 51.25 MB
  //   WT     : 128*512 bf16       = 128 KB
  //   xb     : NN*64 u32          = 12.8 MB
  //   pedges : PART*CAP uint2     = 20.48 MB
  //   epack  : NE u32             = 9.6 MB
  //   off    : RN+1 ints ; cur : RN ints ; pcur : PART ints ; bsum
  char* ws = (char*)d_ws;
  char*  Abf   = ws;                         ws += (size_t)MPAD * KK * 2;
  unsigned short* WT = (unsigned short*)ws;  ws += (size_t)128 * KK * 2;
  unsigned* xb  = (unsigned*)ws;             ws += (size_t)NN * 64 * 4;
  uint2* pedges = (uint2*)ws;                ws += (size_t)PART * CAP * sizeof(uint2);
  unsigned* epack = (unsigned*)ws;           ws += (size_t)NE * 4;
  int*   off   = (int*)ws;                   ws += ((size_t)RN + 4) * sizeof(int);
  int*   cur   = (int*)ws;                   ws += (size_t)RN * sizeof(int);   // cur | pcur contiguous
  int*   pcur  = (int*)ws;                   ws += (size_t)PART * sizeof(int);
  int*   bsum  = (int*)ws;

  int nb = (RN + 1023) / 1024;               // 147 scan blocks

  hipMemsetAsync(cur, 0, (size_t)(RN + PART) * sizeof(int), stream);  // cur + pcur
  build_wt   <<<256, 256, 0, stream>>>(weight, shw, WT);
  build_xb   <<<(NN * 64 + 255) / 256, 256, 0, stream>>>(input, xb);
  part_split <<<(NE + 1023) / 1024, 256, 0, stream>>>(arows, acols, avals,
                                                      cur, pcur, pedges);
  scan_local <<<nb, 256, 0, stream>>>(cur, off, bsum);
  scan_bsums <<<1, 64, 0, stream>>>(bsum, nb);
  scan_apply <<<nb, 256, 0, stream>>>(off, bsum, cur, nb);
  part_scatter<<<2048, 256, 0, stream>>>(pedges, pcur, cur, epack);
  gather_ln  <<<(NN + 3) / 4, 256, 0, stream>>>(xb, epack, off, gamma, beta,
                                                (unsigned*)Abf);
  gemm_mfma  <<<MPAD / 64, 256, 0, stream>>>(Abf, (const char*)WT, bias, out);
}

// Round 6
// 352.942 us; speedup vs baseline: 12.0460x; 1.0094x over previous
//
#include <hip/hip_runtime.h>

// Problem constants (fixed by the reference)
constexpr int NN  = 50000;   // nodes
constexpr int NNZ = 800000;  // edges per relation
constexpr int RR  = 3;       // relations
constexpr int D   = 128;     // feature dim (in == out)
constexpr int RN  = RR * NN; // fine buckets (150000)
constexpr int NE  = RR * NNZ;
constexpr int KK  = 512;     // concat K: 3*128 support + 128 layernorm
constexpr int MPAD = 50048;  // 782 * 64, padded row count for A
constexpr int PART = 16;     // coarse partitions (XCD-local scatter)
constexpr int PSZ  = RN / PART;   // 9375 buckets per partition (exact)
constexpr int CAP  = 160000; // partition capacity (mean 150k)
constexpr int CAPB = 128;    // per-block per-partition LDS staging (mean 64, +8 sigma)
constexpr float EPS = 1e-6f;

using bf16x8 = __attribute__((ext_vector_type(8))) __bf16;
using f32x4  = __attribute__((ext_vector_type(4))) float;

// RNE f32 -> bf16 packing helpers (NaN not possible here)
__device__ __forceinline__ unsigned pack_bf2(float a, float b) {
  unsigned ua = __float_as_uint(a); ua = (ua + (0x7FFFu + ((ua >> 16) & 1))) >> 16;
  unsigned ub = __float_as_uint(b); ub = (ub + (0x7FFFu + ((ub >> 16) & 1))) >> 16;
  return ua | (ub << 16);
}
__device__ __forceinline__ unsigned bf16_lo(float a) {
  unsigned ua = __float_as_uint(a);
  return (ua + (0x7FFFu + ((ua >> 16) & 1))) >> 16;
}

__device__ __forceinline__ void gload16(const void* g, void* l) {
  __builtin_amdgcn_global_load_lds(
      (const __attribute__((address_space(1))) unsigned int*)g,
      (__attribute__((address_space(3))) unsigned int*)l, 16, 0, 0);
}

// ---------------------------------------------------------------------------
// K1: multisplit with LDS staging. Edges -> 16 coarse partitions; payload
// staged in LDS per partition, flushed as contiguous coalesced chunks so
// each pedges cache line is produced whole by one block (kills the 5x
// partial-line writeback amplification). Fuses the fine histogram.
// ---------------------------------------------------------------------------
__global__ __launch_bounds__(256) void part_split(
    const int*   __restrict__ rows,
    const int*   __restrict__ cols,
    const float* __restrict__ vals,
    int* __restrict__ cnt,        // [RN] fine histogram
    int* __restrict__ pcur,       // [PART]
    uint2* __restrict__ pedges) { // [PART*CAP]
  __shared__ int lcur[PART], lbase[PART];
  __shared__ uint2 lbuf[PART][CAPB];          // 16 KB staging
  int t = threadIdx.x;
  if (t < PART) lcur[t] = 0;
  __syncthreads();
  int e0 = blockIdx.x * 1024;
  int ovf_pe[4], ovf_rank[4];                 // rare overflow path
  uint2 ovf_val[4];
  #pragma unroll
  for (int j = 0; j < 4; j++) {
    ovf_pe[j] = -1;
    int e = e0 + j * 256 + t;
    if (e < NE) {
      int r = (e >= 2 * NNZ) ? 2 : (e >= NNZ ? 1 : 0);
      int b = r * NN + rows[e];
      int p = b / PSZ;                        // magic-mul div by 9375
      unsigned pay = ((unsigned)cols[e] << 16) | bf16_lo(vals[e]);
      int rank = atomicAdd(&lcur[p], 1);
      atomicAdd(&cnt[b], 1);                  // fused histogram
      if (rank < CAPB) {
        lbuf[p][rank] = make_uint2((unsigned)b, pay);
      } else {                                // ~1e-8 probability
        ovf_pe[j] = p; ovf_rank[j] = rank;
        ovf_val[j] = make_uint2((unsigned)b, pay);
      }
    }
  }
  __syncthreads();
  if (t < PART) lbase[t] = atomicAdd(&pcur[t], lcur[t]);
  __syncthreads();
  // flush: wave w handles partitions 4w..4w+3, contiguous coalesced stores
  int wid = t >> 6, l = t & 63;
  #pragma unroll
  for (int q = 0; q < 4; q++) {
    int p = wid * 4 + q;
    int n = min(lcur[p], CAPB);
    uint2* dst = pedges + (size_t)p * CAP + lbase[p];
    for (int i = l; i < n; i += 64) dst[i] = lbuf[p][i];
  }
  #pragma unroll
  for (int j = 0; j < 4; j++)
    if (ovf_pe[j] >= 0)
      pedges[(size_t)ovf_pe[j] * CAP + lbase[ovf_pe[j]] + ovf_rank[j]] = ovf_val[j];
}

// ---------------------------------------------------------------------------
// K2a/b/c: hierarchical exclusive scan of the 150k fine counts
// ---------------------------------------------------------------------------
__global__ __launch_bounds__(256) void scan_local(
    const int* __restrict__ cnt, int* __restrict__ off, int* __restrict__ bsum) {
  __shared__ int sdata[256];
  int t = threadIdx.x;
  int base = blockIdx.x * 1024 + t * 4;
  int c[4];
  #pragma unroll
  for (int j = 0; j < 4; j++) c[j] = (base + j < RN) ? cnt[base + j] : 0;
  int s = c[0] + c[1] + c[2] + c[3];
  sdata[t] = s;
  __syncthreads();
  #pragma unroll
  for (int step = 1; step < 256; step <<= 1) {
    int v = (t >= step) ? sdata[t - step] : 0;
    __syncthreads();
    sdata[t] += v;
    __syncthreads();
  }
  int excl = sdata[t] - s;
  if (base + 0 < RN) off[base + 0] = excl;
  if (base + 1 < RN) off[base + 1] = excl + c[0];
  if (base + 2 < RN) off[base + 2] = excl + c[0] + c[1];
  if (base + 3 < RN) off[base + 3] = excl + c[0] + c[1] + c[2];
  if (t == 255) bsum[blockIdx.x] = sdata[255];
}

__global__ __launch_bounds__(64) void scan_bsums(int* __restrict__ bsum, int nb) {
  int l = threadIdx.x;
  int carry = 0;
  for (int base = 0; base < nb; base += 64) {
    int i = base + l;
    int v = (i < nb) ? bsum[i] : 0;
    #pragma unroll
    for (int s = 1; s < 64; s <<= 1) {
      int u = __shfl_up(v, s);
      if (l >= s) v += u;
    }
    int tot = __shfl(v, 63);
    if (i < nb) bsum[i] = v + carry;
    carry += tot;
  }
}

__global__ __launch_bounds__(256) void scan_apply(
    int* __restrict__ off, const int* __restrict__ bsum, int* __restrict__ cur, int nb) {
  int b = blockIdx.x;
  int add = (b > 0) ? bsum[b - 1] : 0;
  int base = b * 1024 + threadIdx.x * 4;
  #pragma unroll
  for (int j = 0; j < 4; j++) {
    int i = base + j;
    if (i < RN) {
      int v = off[i] + add;
      off[i] = v;
      cur[i] = v;
    }
  }
  if (b == 0 && threadIdx.x == 0) off[RN] = bsum[nb - 1];
}

// ---------------------------------------------------------------------------
// K3: XCD-local scatter. blockIdx%16 == partition; its epack region (~600KB)
// and cursors (~37.5KB) stay in one XCD's L2 -> single writeback per line.
// ---------------------------------------------------------------------------
__global__ __launch_bounds__(256) void part_scatter(
    const uint2* __restrict__ pedges,
    const int*   __restrict__ pcur,
    int* __restrict__ cur,
    unsigned* __restrict__ epack) {
  int p = blockIdx.x & 15;
  int n = pcur[p];
  const uint2* src = pedges + (size_t)p * CAP;
  int stride = (gridDim.x >> 4) * 256;
  for (int i = (blockIdx.x >> 4) * 256 + threadIdx.x; i < n; i += stride) {
    uint2 ed = src[i];
    int pos = atomicAdd(&cur[ed.x], 1);
    epack[pos] = ed.y;
  }
}

// ---------------------------------------------------------------------------
// K4pre: x -> bf16 pairs. xb[node*64 + l] = bf16x2(x[node][2l], x[node][2l+1])
// ---------------------------------------------------------------------------
__global__ __launch_bounds__(256) void build_xb(
    const float* __restrict__ x, unsigned* __restrict__ xb) {
  int i = blockIdx.x * 256 + threadIdx.x;
  if (i >= NN * 64) return;
  float2 v = ((const float2*)x)[i];
  xb[i] = pack_bf2(v.x, v.y);
}

// ---------------------------------------------------------------------------
// K4: gather SpMM (3 relations) + sum + LayerNorm, fused. bf16 x, 4B epack.
// One wave per node; lane owns dims {2l, 2l+1}. Emits bf16 A row
// [0..383]=support slabs, [384..511]=LN.
// ---------------------------------------------------------------------------
__global__ __launch_bounds__(256) void gather_ln(
    const unsigned* __restrict__ xb,    // [NN][64] bf16x2
    const unsigned* __restrict__ epack, // [NE] col16|bf16val, bucket-sorted
    const int*      __restrict__ off,   // [RN+1]
    const float* __restrict__ gamma,
    const float* __restrict__ beta,
    unsigned* __restrict__ Au) {        // A as uint view: [MPAD][256]
  int node = blockIdx.x * 4 + (threadIdx.x >> 6);
  if (node >= NN) return;
  int l = threadIdx.x & 63;
  float2 tot = make_float2(0.f, 0.f);
  #pragma unroll
  for (int r = 0; r < RR; r++) {
    int b = r * NN + node;
    int s = off[b], e2 = off[b + 1];
    float2 acc = make_float2(0.f, 0.f);
    int i = s;
    for (; i + 8 <= e2; i += 8) {
      unsigned u0 = epack[i + 0], u1 = epack[i + 1];
      unsigned u2 = epack[i + 2], u3 = epack[i + 3];
      unsigned u4 = epack[i + 4], u5 = epack[i + 5];
      unsigned u6 = epack[i + 6], u7 = epack[i + 7];
      unsigned g0 = xb[(u0 >> 16) * 64 + l];
      unsigned g1 = xb[(u1 >> 16) * 64 + l];
      unsigned g2 = xb[(u2 >> 16) * 64 + l];
      unsigned g3 = xb[(u3 >> 16) * 64 + l];
      unsigned g4 = xb[(u4 >> 16) * 64 + l];
      unsigned g5 = xb[(u5 >> 16) * 64 + l];
      unsigned g6 = xb[(u6 >> 16) * 64 + l];
      unsigned g7 = xb[(u7 >> 16) * 64 + l];
      float v0 = __uint_as_float(u0 << 16), v1 = __uint_as_float(u1 << 16);
      float v2 = __uint_as_float(u2 << 16), v3 = __uint_as_float(u3 << 16);
      float v4 = __uint_as_float(u4 << 16), v5 = __uint_as_float(u5 << 16);
      float v6 = __uint_as_float(u6 << 16), v7 = __uint_as_float(u7 << 16);
      acc.x += v0 * __uint_as_float(g0 << 16) + v1 * __uint_as_float(g1 << 16)
             + v2 * __uint_as_float(g2 << 16) + v3 * __uint_as_float(g3 << 16)
             + v4 * __uint_as_float(g4 << 16) + v5 * __uint_as_float(g5 << 16)
             + v6 * __uint_as_float(g6 << 16) + v7 * __uint_as_float(g7 << 16);
      acc.y += v0 * __uint_as_float(g0 & 0xFFFF0000u) + v1 * __uint_as_float(g1 & 0xFFFF0000u)
             + v2 * __uint_as_float(g2 & 0xFFFF0000u) + v3 * __uint_as_float(g3 & 0xFFFF0000u)
             + v4 * __uint_as_float(g4 & 0xFFFF0000u) + v5 * __uint_as_float(g5 & 0xFFFF0000u)
             + v6 * __uint_as_float(g6 & 0xFFFF0000u) + v7 * __uint_as_float(g7 & 0xFFFF0000u);
    }
    for (; i < e2; i++) {
      unsigned u = epack[i];
      unsigned g = xb[(u >> 16) * 64 + l];
      float v = __uint_as_float(u << 16);
      acc.x += v * __uint_as_float(g << 16);
      acc.y += v * __uint_as_float(g & 0xFFFF0000u);
    }
    Au[(size_t)node * 256 + r * 64 + l] = pack_bf2(acc.x, acc.y);
    tot.x += acc.x;
    tot.y += acc.y;
  }
  float sum = tot.x + tot.y;
  float sq  = tot.x * tot.x + tot.y * tot.y;
  #pragma unroll
  for (int m = 32; m >= 1; m >>= 1) {
    sum += __shfl_xor(sum, m);
    sq  += __shfl_xor(sq,  m);
  }
  float mean = sum * (1.0f / D);
  float var  = sq * (1.0f / D) - mean * mean;
  float rstd = rsqrtf(var + EPS);
  int d = l * 2;
  float o0 = (tot.x - mean) * rstd * gamma[d]     + beta[d];
  float o1 = (tot.y - mean) * rstd * gamma[d + 1] + beta[d + 1];
  Au[(size_t)node * 256 + 192 + l] = pack_bf2(o0, o1);
}

// ---------------------------------------------------------------------------
// K4b: build W^T bf16 [128 cols][512 k]: k<384 from weight, else share_weight
// ---------------------------------------------------------------------------
__global__ __launch_bounds__(256) void build_wt(
    const float* __restrict__ w,    // [384][128]
    const float* __restrict__ shw,  // [128][128]
    unsigned short* __restrict__ WT) { // bf16 [128][512]
  int idx = blockIdx.x * 256 + threadIdx.x;  // 65536
  int k   = idx >> 7;
  int col = idx & 127;
  float v = (k < 384) ? w[k * 128 + col] : shw[(k - 384) * 128 + col];
  WT[col * 512 + k] = (unsigned short)bf16_lo(v);
}

// ---------------------------------------------------------------------------
// K5: bf16 MFMA GEMM.  out = 0.5 * A[50000][512] @ W[512][128] + bias
// BM=64, BN=128 (full), BK=64. 4 waves (2x2), each wave 32 rows x 64 cols.
// ---------------------------------------------------------------------------
__global__ __launch_bounds__(256) void gemm_mfma(
    const char* __restrict__ Ab,    // bf16 [MPAD][512] as bytes
    const char* __restrict__ Bb,    // bf16 [128][512] (W^T) as bytes
    const float* __restrict__ bias, // [128]
    float* __restrict__ out) {      // [NN][128]
  __shared__ __align__(16) char smem[24576];   // As 8KB | Bs 16KB
  char* As = smem;
  char* Bs = smem + 8192;

  int tid  = threadIdx.x;
  int wid  = tid >> 6;
  int lane = tid & 63;
  int wr   = wid >> 1;
  int wc   = wid & 1;
  int row0 = blockIdx.x * 64;

  f32x4 zero = {0.f, 0.f, 0.f, 0.f};
  f32x4 acc[2][4];
  #pragma unroll
  for (int i = 0; i < 2; i++)
    #pragma unroll
    for (int j = 0; j < 4; j++) acc[i][j] = zero;

  for (int kc = 0; kc < 8; kc++) {
    #pragma unroll
    for (int i = 0; i < 2; i++) {
      int c = i * 256 + tid;
      int r = c >> 3, s = c & 7;
      int ss = s ^ (r & 7);
      const void* src = Ab + (size_t)(row0 + r) * 1024 + kc * 128 + ss * 16;
      void* dst = As + i * 4096 + wid * 1024;
      gload16(src, dst);
    }
    #pragma unroll
    for (int i = 0; i < 4; i++) {
      int c = i * 256 + tid;
      int r = c >> 3, s = c & 7;
      int ss = s ^ (r & 7);
      const void* src = Bb + (size_t)r * 1024 + kc * 128 + ss * 16;
      void* dst = Bs + i * 4096 + wid * 1024;
      gload16(src, dst);
    }
    __syncthreads();

    #pragma unroll
    for (int ks = 0; ks < 2; ks++) {
      bf16x8 afrag[2], bfrag[4];
      int sg = ks * 4 + (lane >> 4);
      #pragma unroll
      for (int rb = 0; rb < 2; rb++) {
        int r = wr * 32 + rb * 16 + (lane & 15);
        afrag[rb] = *(const bf16x8*)(As + r * 128 + (sg ^ (r & 7)) * 16);
      }
      #pragma unroll
      for (int cb = 0; cb < 4; cb++) {
        int col = wc * 64 + cb * 16 + (lane & 15);
        bfrag[cb] = *(const bf16x8*)(Bs + col * 128 + (sg ^ (col & 7)) * 16);
      }
      #pragma unroll
      for (int rb = 0; rb < 2; rb++)
        #pragma unroll
        for (int cb = 0; cb < 4; cb++)
          acc[rb][cb] = __builtin_amdgcn_mfma_f32_16x16x32_bf16(
              afrag[rb], bfrag[cb], acc[rb][cb], 0, 0, 0);
    }
    __syncthreads();
  }

  #pragma unroll
  for (int rb = 0; rb < 2; rb++) {
    #pragma unroll
    for (int cb = 0; cb < 4; cb++) {
      int col = wc * 64 + cb * 16 + (lane & 15);
      float bv = bias[col];
      #pragma unroll
      for (int r = 0; r < 4; r++) {
        int grow = row0 + wr * 32 + rb * 16 + (lane >> 4) * 4 + r;
        if (grow < NN) out[(size_t)grow * 128 + col] = 0.5f * acc[rb][cb][r] + bv;
      }
    }
  }
}

// ---------------------------------------------------------------------------
extern "C" void kernel_launch(void* const* d_in, const int* in_sizes, int n_in,
                              void* d_out, int out_size, void* d_ws, size_t ws_size,
                              hipStream_t stream) {
  const float* input  = (const float*)d_in[0];
  const int*   arows  = (const int*)  d_in[1];
  const int*   acols  = (const int*)  d_in[2];
  const float* avals  = (const float*)d_in[3];
  const float* weight = (const float*)d_in[4];
  const float* shw    = (const float*)d_in[5];
  const float* bias   = (const float*)d_in[6];
  const float* gamma  = (const float*)d_in[7];
  const float* beta   = (const float*)d_in[8];
  float* out = (float*)d_out;

  // Workspace layout (~95.5 MB):
  //   A      : MPAD*512 bf16      = 51.25 MB
  //   WT     : 128*512 bf16       = 128 KB
  //   xb     : NN*64 u32          = 12.8 MB
  //   pedges : PART*CAP uint2     = 20.48 MB
  //   epack  : NE u32             = 9.6 MB
  //   off    : RN+1 ints ; cur : RN ints ; pcur : PART ints ; bsum
  char* ws = (char*)d_ws;
  char*  Abf   = ws;                         ws += (size_t)MPAD * KK * 2;
  unsigned short* WT = (unsigned short*)ws;  ws += (size_t)128 * KK * 2;
  unsigned* xb  = (unsigned*)ws;             ws += (size_t)NN * 64 * 4;
  uint2* pedges = (uint2*)ws;                ws += (size_t)PART * CAP * sizeof(uint2);
  unsigned* epack = (unsigned*)ws;           ws += (size_t)NE * 4;
  int*   off   = (int*)ws;                   ws += ((size_t)RN + 4) * sizeof(int);
  int*   cur   = (int*)ws;                   ws += (size_t)RN * sizeof(int);   // cur | pcur contiguous
  int*   pcur  = (int*)ws;                   ws += (size_t)PART * sizeof(int);
  int*   bsum  = (int*)ws;

  int nb = (RN + 1023) / 1024;               // 147 scan blocks

  hipMemsetAsync(cur, 0, (size_t)(RN + PART) * sizeof(int), stream);  // cur + pcur
  build_wt   <<<256, 256, 0, stream>>>(weight, shw, WT);
  build_xb   <<<(NN * 64 + 255) / 256, 256, 0, stream>>>(input, xb);
  part_split <<<(NE + 1023) / 1024, 256, 0, stream>>>(arows, acols, avals,
                                                      cur, pcur, pedges);
  scan_local <<<nb, 256, 0, stream>>>(cur, off, bsum);
  scan_bsums <<<1, 64, 0, stream>>>(bsum, nb);
  scan_apply <<<nb, 256, 0, stream>>>(off, bsum, cur, nb);
  part_scatter<<<2048, 256, 0, stream>>>(pedges, pcur, cur, epack);
  gather_ln  <<<(NN + 3) / 4, 256, 0, stream>>>(xb, epack, off, gamma, beta,
                                                (unsigned*)Abf);
  gemm_mfma  <<<MPAD / 64, 256, 0, stream>>>(Abf, (const char*)WT, bias, out);
}

// Round 7
// 321.058 us; speedup vs baseline: 13.2422x; 1.0993x over previous
//
#include <hip/hip_runtime.h>

// Problem constants (fixed by the reference)
constexpr int NN  = 50000;   // nodes
constexpr int NNZ = 800000;  // edges per relation
constexpr int RR  = 3;       // relations
constexpr int D   = 128;     // feature dim (in == out)
constexpr int RN  = RR * NN; // fine buckets (150000)
constexpr int NE  = RR * NNZ;
constexpr int KK  = 512;     // concat K: 3*128 support + 128 layernorm
constexpr int MPAD = 50048;  // 782 * 64, padded row count for A
constexpr int PART = 32;     // coarse partitions
constexpr int PSZ  = (RN + PART - 1) / PART;  // 4688 buckets per partition
constexpr int CAP  = 80000;  // partition capacity (mean 75008, sd ~270)
constexpr int CAPB = 80;     // per-block per-partition LDS staging (mean 32, +8.6 sigma)
constexpr float EPS = 1e-6f;

using bf16x8 = __attribute__((ext_vector_type(8))) __bf16;
using f32x4  = __attribute__((ext_vector_type(4))) float;

// RNE f32 -> bf16 packing helpers (NaN not possible here)
__device__ __forceinline__ unsigned pack_bf2(float a, float b) {
  unsigned ua = __float_as_uint(a); ua = (ua + (0x7FFFu + ((ua >> 16) & 1))) >> 16;
  unsigned ub = __float_as_uint(b); ub = (ub + (0x7FFFu + ((ub >> 16) & 1))) >> 16;
  return ua | (ub << 16);
}
__device__ __forceinline__ unsigned bf16_lo(float a) {
  unsigned ua = __float_as_uint(a);
  return (ua + (0x7FFFu + ((ua >> 16) & 1))) >> 16;
}

__device__ __forceinline__ void gload16(const void* g, void* l) {
  __builtin_amdgcn_global_load_lds(
      (const __attribute__((address_space(1))) unsigned int*)g,
      (__attribute__((address_space(3))) unsigned int*)l, 16, 0, 0);
}

// ---------------------------------------------------------------------------
// K1: multisplit. Edges -> 32 coarse partitions via LDS ranking + staging.
// NO scattered global atomics (the fine histogram is gone - sort_part
// rebuilds it in LDS). Only 32 pcur atomics per block.
// ---------------------------------------------------------------------------
__global__ __launch_bounds__(256) void part_split(
    const int*   __restrict__ rows,
    const int*   __restrict__ cols,
    const float* __restrict__ vals,
    int* __restrict__ pcur,       // [PART]
    uint2* __restrict__ pedges) { // [PART*CAP]
  __shared__ int lcur[PART], lbase[PART];
  __shared__ uint2 lbuf[PART][CAPB];          // 20 KB staging
  int t = threadIdx.x;
  if (t < PART) lcur[t] = 0;
  __syncthreads();
  int e0 = blockIdx.x * 1024;
  int ovf_pe[4], ovf_rank[4];                 // rare overflow path
  uint2 ovf_val[4];
  #pragma unroll
  for (int j = 0; j < 4; j++) {
    ovf_pe[j] = -1;
    int e = e0 + j * 256 + t;
    if (e < NE) {
      int r = (e >= 2 * NNZ) ? 2 : (e >= NNZ ? 1 : 0);
      int b = r * NN + rows[e];
      int p = b / PSZ;                        // magic-mul div
      unsigned pay = ((unsigned)cols[e] << 16) | bf16_lo(vals[e]);
      int rank = atomicAdd(&lcur[p], 1);
      if (rank < CAPB) {
        lbuf[p][rank] = make_uint2((unsigned)b, pay);
      } else {                                // ~1e-15 probability
        ovf_pe[j] = p; ovf_rank[j] = rank;
        ovf_val[j] = make_uint2((unsigned)b, pay);
      }
    }
  }
  __syncthreads();
  if (t < PART) lbase[t] = atomicAdd(&pcur[t], lcur[t]);
  __syncthreads();
  // flush: wave w handles partitions 8w..8w+7, contiguous coalesced stores
  int wid = t >> 6, l = t & 63;
  #pragma unroll
  for (int q = 0; q < 8; q++) {
    int p = wid * 8 + q;
    int n = min(lcur[p], CAPB);
    uint2* dst = pedges + (size_t)p * CAP + lbase[p];
    for (int i = l; i < n; i += 64) dst[i] = lbuf[p][i];
  }
  #pragma unroll
  for (int j = 0; j < 4; j++)
    if (ovf_pe[j] >= 0)
      pedges[(size_t)ovf_pe[j] * CAP + lbase[ovf_pe[j]] + ovf_rank[j]] = ovf_val[j];
}

// ---------------------------------------------------------------------------
// K2: exclusive scan of the 32 partition totals (single wave); off[RN] = NE.
// ---------------------------------------------------------------------------
__global__ __launch_bounds__(64) void psum(
    const int* __restrict__ pcur, int* __restrict__ pbase, int* __restrict__ off) {
  int l = threadIdx.x;
  int v = (l < PART) ? pcur[l] : 0;
  int inc = v;
  #pragma unroll
  for (int s = 1; s < 64; s <<= 1) {
    int u = __shfl_up(inc, s);
    if (l >= s) inc += u;
  }
  if (l < PART) pbase[l] = inc - v;
  if (l == 0) off[RN] = NE;
}

// ---------------------------------------------------------------------------
// K3: per-partition LDS counting sort. One block per partition:
//  pass 1: histogram partition edges into sc[4688] (LDS atomics)
//  scan:   block exclusive scan of sc -> global offsets (write off[])
//  pass 2: counting-sort edges into epack via LDS cursors.
// Zero scattered global atomics.
// ---------------------------------------------------------------------------
__global__ __launch_bounds__(256) void sort_part(
    const uint2* __restrict__ pedges,
    const int*   __restrict__ pcur,
    const int*   __restrict__ pbase,
    int* __restrict__ off,
    unsigned* __restrict__ epack) {
  __shared__ int sc[PSZ];        // 18.75 KB counts -> cursors
  __shared__ int sdata[256];
  int p = blockIdx.x;
  int t = threadIdx.x;
  int bb = p * PSZ;                         // first bucket of partition
  int nbuck = min(PSZ, RN - bb);
  int n = pcur[p];
  int gbase = pbase[p];
  const uint2* src = pedges + (size_t)p * CAP;

  for (int i = t; i < nbuck; i += 256) sc[i] = 0;
  __syncthreads();
  for (int i = t; i < n; i += 256)
    atomicAdd(&sc[src[i].x - bb], 1);
  __syncthreads();

  // block exclusive scan over sc[0..nbuck)
  constexpr int PER = (PSZ + 255) / 256;    // 19
  int lo = t * PER, hi = min(lo + PER, nbuck);
  int s = 0;
  for (int i = lo; i < hi; i++) s += sc[i];
  sdata[t] = s;
  __syncthreads();
  #pragma unroll
  for (int step = 1; step < 256; step <<= 1) {
    int v = (t >= step) ? sdata[t - step] : 0;
    __syncthreads();
    sdata[t] += v;
    __syncthreads();
  }
  int run = gbase + sdata[t] - s;           // global start of this thread's range
  for (int i = lo; i < hi; i++) {
    int c = sc[i];
    sc[i] = run;                            // cursor start
    off[bb + i] = run;
    run += c;
  }
  __syncthreads();

  // pass 2: scatter into epack (stays in this XCD's L2, ~300KB)
  for (int i = t; i < n; i += 256) {
    uint2 ed = src[i];
    int pos = atomicAdd(&sc[ed.x - bb], 1);
    epack[pos] = ed.y;
  }
}

// ---------------------------------------------------------------------------
// K4pre: x -> bf16 pairs. xb[node*64 + l] = bf16x2(x[node][2l], x[node][2l+1])
// ---------------------------------------------------------------------------
__global__ __launch_bounds__(256) void build_xb(
    const float* __restrict__ x, unsigned* __restrict__ xb) {
  int i = blockIdx.x * 256 + threadIdx.x;
  if (i >= NN * 64) return;
  float2 v = ((const float2*)x)[i];
  xb[i] = pack_bf2(v.x, v.y);
}

// ---------------------------------------------------------------------------
// K4: gather SpMM (3 relations) + sum + LayerNorm, fused. bf16 x, 4B epack.
// One wave per node; lane owns dims {2l, 2l+1}. Emits bf16 A row
// [0..383]=support slabs, [384..511]=LN.
// ---------------------------------------------------------------------------
__global__ __launch_bounds__(256) void gather_ln(
    const unsigned* __restrict__ xb,    // [NN][64] bf16x2
    const unsigned* __restrict__ epack, // [NE] col16|bf16val, bucket-sorted
    const int*      __restrict__ off,   // [RN+1]
    const float* __restrict__ gamma,
    const float* __restrict__ beta,
    unsigned* __restrict__ Au) {        // A as uint view: [MPAD][256]
  int node = blockIdx.x * 4 + (threadIdx.x >> 6);
  if (node >= NN) return;
  int l = threadIdx.x & 63;
  float2 tot = make_float2(0.f, 0.f);
  #pragma unroll
  for (int r = 0; r < RR; r++) {
    int b = r * NN + node;
    int s = off[b], e2 = off[b + 1];
    float2 acc = make_float2(0.f, 0.f);
    int i = s;
    for (; i + 8 <= e2; i += 8) {
      unsigned u0 = epack[i + 0], u1 = epack[i + 1];
      unsigned u2 = epack[i + 2], u3 = epack[i + 3];
      unsigned u4 = epack[i + 4], u5 = epack[i + 5];
      unsigned u6 = epack[i + 6], u7 = epack[i + 7];
      unsigned g0 = xb[(u0 >> 16) * 64 + l];
      unsigned g1 = xb[(u1 >> 16) * 64 + l];
      unsigned g2 = xb[(u2 >> 16) * 64 + l];
      unsigned g3 = xb[(u3 >> 16) * 64 + l];
      unsigned g4 = xb[(u4 >> 16) * 64 + l];
      unsigned g5 = xb[(u5 >> 16) * 64 + l];
      unsigned g6 = xb[(u6 >> 16) * 64 + l];
      unsigned g7 = xb[(u7 >> 16) * 64 + l];
      float v0 = __uint_as_float(u0 << 16), v1 = __uint_as_float(u1 << 16);
      float v2 = __uint_as_float(u2 << 16), v3 = __uint_as_float(u3 << 16);
      float v4 = __uint_as_float(u4 << 16), v5 = __uint_as_float(u5 << 16);
      float v6 = __uint_as_float(u6 << 16), v7 = __uint_as_float(u7 << 16);
      acc.x += v0 * __uint_as_float(g0 << 16) + v1 * __uint_as_float(g1 << 16)
             + v2 * __uint_as_float(g2 << 16) + v3 * __uint_as_float(g3 << 16)
             + v4 * __uint_as_float(g4 << 16) + v5 * __uint_as_float(g5 << 16)
             + v6 * __uint_as_float(g6 << 16) + v7 * __uint_as_float(g7 << 16);
      acc.y += v0 * __uint_as_float(g0 & 0xFFFF0000u) + v1 * __uint_as_float(g1 & 0xFFFF0000u)
             + v2 * __uint_as_float(g2 & 0xFFFF0000u) + v3 * __uint_as_float(g3 & 0xFFFF0000u)
             + v4 * __uint_as_float(g4 & 0xFFFF0000u) + v5 * __uint_as_float(g5 & 0xFFFF0000u)
             + v6 * __uint_as_float(g6 & 0xFFFF0000u) + v7 * __uint_as_float(g7 & 0xFFFF0000u);
    }
    for (; i < e2; i++) {
      unsigned u = epack[i];
      unsigned g = xb[(u >> 16) * 64 + l];
      float v = __uint_as_float(u << 16);
      acc.x += v * __uint_as_float(g << 16);
      acc.y += v * __uint_as_float(g & 0xFFFF0000u);
    }
    Au[(size_t)node * 256 + r * 64 + l] = pack_bf2(acc.x, acc.y);
    tot.x += acc.x;
    tot.y += acc.y;
  }
  float sum = tot.x + tot.y;
  float sq  = tot.x * tot.x + tot.y * tot.y;
  #pragma unroll
  for (int m = 32; m >= 1; m >>= 1) {
    sum += __shfl_xor(sum, m);
    sq  += __shfl_xor(sq,  m);
  }
  float mean = sum * (1.0f / D);
  float var  = sq * (1.0f / D) - mean * mean;
  float rstd = rsqrtf(var + EPS);
  int d = l * 2;
  float o0 = (tot.x - mean) * rstd * gamma[d]     + beta[d];
  float o1 = (tot.y - mean) * rstd * gamma[d + 1] + beta[d + 1];
  Au[(size_t)node * 256 + 192 + l] = pack_bf2(o0, o1);
}

// ---------------------------------------------------------------------------
// K4b: build W^T bf16 [128 cols][512 k]: k<384 from weight, else share_weight
// ---------------------------------------------------------------------------
__global__ __launch_bounds__(256) void build_wt(
    const float* __restrict__ w,    // [384][128]
    const float* __restrict__ shw,  // [128][128]
    unsigned short* __restrict__ WT) { // bf16 [128][512]
  int idx = blockIdx.x * 256 + threadIdx.x;  // 65536
  int k   = idx >> 7;
  int col = idx & 127;
  float v = (k < 384) ? w[k * 128 + col] : shw[(k - 384) * 128 + col];
  WT[col * 512 + k] = (unsigned short)bf16_lo(v);
}

// ---------------------------------------------------------------------------
// K5: bf16 MFMA GEMM.  out = 0.5 * A[50000][512] @ W[512][128] + bias
// BM=64, BN=128 (full), BK=64. 4 waves (2x2), each wave 32 rows x 64 cols.
// ---------------------------------------------------------------------------
__global__ __launch_bounds__(256) void gemm_mfma(
    const char* __restrict__ Ab,    // bf16 [MPAD][512] as bytes
    const char* __restrict__ Bb,    // bf16 [128][512] (W^T) as bytes
    const float* __restrict__ bias, // [128]
    float* __restrict__ out) {      // [NN][128]
  __shared__ __align__(16) char smem[24576];   // As 8KB | Bs 16KB
  char* As = smem;
  char* Bs = smem + 8192;

  int tid  = threadIdx.x;
  int wid  = tid >> 6;
  int lane = tid & 63;
  int wr   = wid >> 1;
  int wc   = wid & 1;
  int row0 = blockIdx.x * 64;

  f32x4 zero = {0.f, 0.f, 0.f, 0.f};
  f32x4 acc[2][4];
  #pragma unroll
  for (int i = 0; i < 2; i++)
    #pragma unroll
    for (int j = 0; j < 4; j++) acc[i][j] = zero;

  for (int kc = 0; kc < 8; kc++) {
    #pragma unroll
    for (int i = 0; i < 2; i++) {
      int c = i * 256 + tid;
      int r = c >> 3, s = c & 7;
      int ss = s ^ (r & 7);
      const void* src = Ab + (size_t)(row0 + r) * 1024 + kc * 128 + ss * 16;
      void* dst = As + i * 4096 + wid * 1024;
      gload16(src, dst);
    }
    #pragma unroll
    for (int i = 0; i < 4; i++) {
      int c = i * 256 + tid;
      int r = c >> 3, s = c & 7;
      int ss = s ^ (r & 7);
      const void* src = Bb + (size_t)r * 1024 + kc * 128 + ss * 16;
      void* dst = Bs + i * 4096 + wid * 1024;
      gload16(src, dst);
    }
    __syncthreads();

    #pragma unroll
    for (int ks = 0; ks < 2; ks++) {
      bf16x8 afrag[2], bfrag[4];
      int sg = ks * 4 + (lane >> 4);
      #pragma unroll
      for (int rb = 0; rb < 2; rb++) {
        int r = wr * 32 + rb * 16 + (lane & 15);
        afrag[rb] = *(const bf16x8*)(As + r * 128 + (sg ^ (r & 7)) * 16);
      }
      #pragma unroll
      for (int cb = 0; cb < 4; cb++) {
        int col = wc * 64 + cb * 16 + (lane & 15);
        bfrag[cb] = *(const bf16x8*)(Bs + col * 128 + (sg ^ (col & 7)) * 16);
      }
      #pragma unroll
      for (int rb = 0; rb < 2; rb++)
        #pragma unroll
        for (int cb = 0; cb < 4; cb++)
          acc[rb][cb] = __builtin_amdgcn_mfma_f32_16x16x32_bf16(
              afrag[rb], bfrag[cb], acc[rb][cb], 0, 0, 0);
    }
    __syncthreads();
  }

  #pragma unroll
  for (int rb = 0; rb < 2; rb++) {
    #pragma unroll
    for (int cb = 0; cb < 4; cb++) {
      int col = wc * 64 + cb * 16 + (lane & 15);
      float bv = bias[col];
      #pragma unroll
      for (int r = 0; r < 4; r++) {
        int grow = row0 + wr * 32 + rb * 16 + (lane >> 4) * 4 + r;
        if (grow < NN) out[(size_t)grow * 128 + col] = 0.5f * acc[rb][cb][r] + bv;
      }
    }
  }
}

// ---------------------------------------------------------------------------
extern "C" void kernel_launch(void* const* d_in, const int* in_sizes, int n_in,
                              void* d_out, int out_size, void* d_ws, size_t ws_size,
                              hipStream_t stream) {
  const float* input  = (const float*)d_in[0];
  const int*   arows  = (const int*)  d_in[1];
  const int*   acols  = (const int*)  d_in[2];
  const float* avals  = (const float*)d_in[3];
  const float* weight = (const float*)d_in[4];
  const float* shw    = (const float*)d_in[5];
  const float* bias   = (const float*)d_in[6];
  const float* gamma  = (const float*)d_in[7];
  const float* beta   = (const float*)d_in[8];
  float* out = (float*)d_out;

  // Workspace layout (~95 MB):
  //   A      : MPAD*512 bf16      = 51.25 MB
  //   WT     : 128*512 bf16       = 128 KB
  //   xb     : NN*64 u32          = 12.8 MB
  //   pedges : PART*CAP uint2     = 20.48 MB
  //   epack  : NE u32             = 9.6 MB
  //   off    : RN+1 ints ; pcur : PART ; pbase : PART
  char* ws = (char*)d_ws;
  char*  Abf   = ws;                         ws += (size_t)MPAD * KK * 2;
  unsigned short* WT = (unsigned short*)ws;  ws += (size_t)128 * KK * 2;
  unsigned* xb  = (unsigned*)ws;             ws += (size_t)NN * 64 * 4;
  uint2* pedges = (uint2*)ws;                ws += (size_t)PART * CAP * sizeof(uint2);
  unsigned* epack = (unsigned*)ws;           ws += (size_t)NE * 4;
  int*   off   = (int*)ws;                   ws += ((size_t)RN + 4) * sizeof(int);
  int*   pcur  = (int*)ws;                   ws += (size_t)PART * sizeof(int);
  int*   pbase = (int*)ws;                   ws += (size_t)PART * sizeof(int);

  hipMemsetAsync(pcur, 0, (size_t)PART * sizeof(int), stream);
  build_wt   <<<256, 256, 0, stream>>>(weight, shw, WT);
  build_xb   <<<(NN * 64 + 255) / 256, 256, 0, stream>>>(input, xb);
  part_split <<<(NE + 1023) / 1024, 256, 0, stream>>>(arows, acols, avals,
                                                      pcur, pedges);
  psum       <<<1, 64, 0, stream>>>(pcur, pbase, off);
  sort_part  <<<PART, 256, 0, stream>>>(pedges, pcur, pbase, off, epack);
  gather_ln  <<<(NN + 3) / 4, 256, 0, stream>>>(xb, epack, off, gamma, beta,
                                                (unsigned*)Abf);
  gemm_mfma  <<<MPAD / 64, 256, 0, stream>>>(Abf, (const char*)WT, bias, out);
}

// Round 8
// 207.235 us; speedup vs baseline: 20.5155x; 1.5492x over previous
//
#include <hip/hip_runtime.h>

// Problem constants (fixed by the reference)
constexpr int NN  = 50000;   // nodes
constexpr int NNZ = 800000;  // edges per relation
constexpr int RR  = 3;       // relations
constexpr int D   = 128;     // feature dim (in == out)
constexpr int RN  = RR * NN; // fine buckets (150000)
constexpr int NE  = RR * NNZ;
constexpr int KK  = 512;     // concat K: 3*128 support + 128 layernorm
constexpr int MPAD = 50048;  // 782 * 64, padded row count for A
constexpr int PART = 256;    // coarse partitions (1 sort block per CU)
constexpr int PSZ  = (RN + PART - 1) / PART;  // 586 buckets per partition
constexpr int CAP  = 10240;  // partition capacity (mean 9375, sd ~97, +8.9 sigma)
constexpr int EPB  = 2048;   // edges per part_split block
constexpr int CAPB = 24;     // per-block per-partition staging (mean 8, +5.7 sigma)
constexpr float EPS = 1e-6f;

using bf16x8 = __attribute__((ext_vector_type(8))) __bf16;
using f32x4  = __attribute__((ext_vector_type(4))) float;

// RNE f32 -> bf16 packing helpers (NaN not possible here)
__device__ __forceinline__ unsigned pack_bf2(float a, float b) {
  unsigned ua = __float_as_uint(a); ua = (ua + (0x7FFFu + ((ua >> 16) & 1))) >> 16;
  unsigned ub = __float_as_uint(b); ub = (ub + (0x7FFFu + ((ub >> 16) & 1))) >> 16;
  return ua | (ub << 16);
}
__device__ __forceinline__ unsigned bf16_lo(float a) {
  unsigned ua = __float_as_uint(a);
  return (ua + (0x7FFFu + ((ua >> 16) & 1))) >> 16;
}

__device__ __forceinline__ void gload16(const void* g, void* l) {
  __builtin_amdgcn_global_load_lds(
      (const __attribute__((address_space(1))) unsigned int*)g,
      (__attribute__((address_space(3))) unsigned int*)l, 16, 0, 0);
}

// ---------------------------------------------------------------------------
// K1: multisplit. Edges -> 256 coarse partitions via LDS ranking + staging.
// No scattered global atomics; 256 pcur atomics per block.
// ---------------------------------------------------------------------------
__global__ __launch_bounds__(256) void part_split(
    const int*   __restrict__ rows,
    const int*   __restrict__ cols,
    const float* __restrict__ vals,
    int* __restrict__ pcur,       // [PART]
    uint2* __restrict__ pedges) { // [PART*CAP]
  __shared__ int lcur[PART], lbase[PART];
  __shared__ uint2 lbuf[PART][CAPB];          // 48 KB staging
  int t = threadIdx.x;
  lcur[t] = 0;
  __syncthreads();
  int e0 = blockIdx.x * EPB;
  constexpr int EPT = EPB / 256;              // 8 edges per thread
  int ovf_pe[EPT], ovf_rank[EPT];             // rare overflow path
  uint2 ovf_val[EPT];
  #pragma unroll
  for (int j = 0; j < EPT; j++) {
    ovf_pe[j] = -1;
    int e = e0 + j * 256 + t;
    if (e < NE) {
      int r = (e >= 2 * NNZ) ? 2 : (e >= NNZ ? 1 : 0);
      int b = r * NN + rows[e];
      int p = b / PSZ;                        // magic-mul div
      unsigned pay = ((unsigned)cols[e] << 16) | bf16_lo(vals[e]);
      int rank = atomicAdd(&lcur[p], 1);
      if (rank < CAPB) {
        lbuf[p][rank] = make_uint2((unsigned)b, pay);
      } else {                                // ~6e-9 per partition-block
        ovf_pe[j] = p; ovf_rank[j] = rank;
        ovf_val[j] = make_uint2((unsigned)b, pay);
      }
    }
  }
  __syncthreads();
  lbase[t] = atomicAdd(&pcur[t], lcur[t]);
  __syncthreads();
  // flush: wave w handles partitions 64w..64w+63, contiguous stores
  int wid = t >> 6, l = t & 63;
  for (int q = 0; q < 64; q++) {
    int p = wid * 64 + q;
    int n = min(lcur[p], CAPB);
    uint2* dst = pedges + (size_t)p * CAP + lbase[p];
    for (int i = l; i < n; i += 64) dst[i] = lbuf[p][i];
  }
  #pragma unroll
  for (int j = 0; j < EPT; j++)
    if (ovf_pe[j] >= 0)
      pedges[(size_t)ovf_pe[j] * CAP + lbase[ovf_pe[j]] + ovf_rank[j]] = ovf_val[j];
}

// ---------------------------------------------------------------------------
// K2: exclusive scan of the 256 partition totals (single wave, 4 chunks).
// ---------------------------------------------------------------------------
__global__ __launch_bounds__(64) void psum(
    const int* __restrict__ pcur, int* __restrict__ pbase, int* __restrict__ off) {
  int l = threadIdx.x;
  int carry = 0;
  for (int base = 0; base < PART; base += 64) {
    int v = pcur[base + l];
    int inc = v;
    #pragma unroll
    for (int s = 1; s < 64; s <<= 1) {
      int u = __shfl_up(inc, s);
      if (l >= s) inc += u;
    }
    pbase[base + l] = inc - v + carry;
    carry += __shfl(inc, 63);
  }
  if (l == 0) off[RN] = NE;
}

// ---------------------------------------------------------------------------
// K3: per-partition LDS counting sort. One block per partition (256 blocks):
//  pass 1: histogram ~9.4k edges into sc[586] (LDS atomics)
//  scan:   block exclusive scan of sc -> global offsets (write off[])
//  pass 2: counting-sort edges into epack via LDS cursors.
// Zero scattered global atomics.
// ---------------------------------------------------------------------------
__global__ __launch_bounds__(256) void sort_part(
    const uint2* __restrict__ pedges,
    const int*   __restrict__ pcur,
    const int*   __restrict__ pbase,
    int* __restrict__ off,
    unsigned* __restrict__ epack) {
  __shared__ int sc[PSZ];        // 2.3 KB counts -> cursors
  __shared__ int sdata[256];
  int p = blockIdx.x;
  int t = threadIdx.x;
  int bb = p * PSZ;                         // first bucket of partition
  int nbuck = min(PSZ, RN - bb);
  int n = pcur[p];
  int gbase = pbase[p];
  const uint2* src = pedges + (size_t)p * CAP;

  for (int i = t; i < nbuck; i += 256) sc[i] = 0;
  __syncthreads();
  for (int i = t; i < n; i += 256)
    atomicAdd(&sc[src[i].x - bb], 1);
  __syncthreads();

  // block exclusive scan over sc[0..nbuck)
  constexpr int PER = (PSZ + 255) / 256;    // 3
  int lo = t * PER, hi = min(lo + PER, nbuck);
  int s = 0;
  for (int i = lo; i < hi; i++) s += sc[i];
  sdata[t] = s;
  __syncthreads();
  #pragma unroll
  for (int step = 1; step < 256; step <<= 1) {
    int v = (t >= step) ? sdata[t - step] : 0;
    __syncthreads();
    sdata[t] += v;
    __syncthreads();
  }
  int run = gbase + sdata[t] - s;           // global start of this thread's range
  for (int i = lo; i < hi; i++) {
    int c = sc[i];
    sc[i] = run;                            // cursor start
    off[bb + i] = run;
    run += c;
  }
  __syncthreads();

  // pass 2: scatter into epack (stays in this XCD's L2, ~37.5KB window)
  for (int i = t; i < n; i += 256) {
    uint2 ed = src[i];
    int pos = atomicAdd(&sc[ed.x - bb], 1);
    epack[pos] = ed.y;
  }
}

// ---------------------------------------------------------------------------
// K4pre: x -> bf16 pairs. xb[node*64 + l] = bf16x2(x[node][2l], x[node][2l+1])
// ---------------------------------------------------------------------------
__global__ __launch_bounds__(256) void build_xb(
    const float* __restrict__ x, unsigned* __restrict__ xb) {
  int i = blockIdx.x * 256 + threadIdx.x;
  if (i >= NN * 64) return;
  float2 v = ((const float2*)x)[i];
  xb[i] = pack_bf2(v.x, v.y);
}

// ---------------------------------------------------------------------------
// K4: gather SpMM (3 relations) + sum + LayerNorm, fused. bf16 x, 4B epack.
// One wave per node; lane owns dims {2l, 2l+1}. Emits bf16 A row
// [0..383]=support slabs, [384..511]=LN.
// ---------------------------------------------------------------------------
__global__ __launch_bounds__(256) void gather_ln(
    const unsigned* __restrict__ xb,    // [NN][64] bf16x2
    const unsigned* __restrict__ epack, // [NE] col16|bf16val, bucket-sorted
    const int*      __restrict__ off,   // [RN+1]
    const float* __restrict__ gamma,
    const float* __restrict__ beta,
    unsigned* __restrict__ Au) {        // A as uint view: [MPAD][256]
  int node = blockIdx.x * 4 + (threadIdx.x >> 6);
  if (node >= NN) return;
  int l = threadIdx.x & 63;
  float2 tot = make_float2(0.f, 0.f);
  #pragma unroll
  for (int r = 0; r < RR; r++) {
    int b = r * NN + node;
    int s = off[b], e2 = off[b + 1];
    float2 acc = make_float2(0.f, 0.f);
    int i = s;
    for (; i + 8 <= e2; i += 8) {
      unsigned u0 = epack[i + 0], u1 = epack[i + 1];
      unsigned u2 = epack[i + 2], u3 = epack[i + 3];
      unsigned u4 = epack[i + 4], u5 = epack[i + 5];
      unsigned u6 = epack[i + 6], u7 = epack[i + 7];
      unsigned g0 = xb[(u0 >> 16) * 64 + l];
      unsigned g1 = xb[(u1 >> 16) * 64 + l];
      unsigned g2 = xb[(u2 >> 16) * 64 + l];
      unsigned g3 = xb[(u3 >> 16) * 64 + l];
      unsigned g4 = xb[(u4 >> 16) * 64 + l];
      unsigned g5 = xb[(u5 >> 16) * 64 + l];
      unsigned g6 = xb[(u6 >> 16) * 64 + l];
      unsigned g7 = xb[(u7 >> 16) * 64 + l];
      float v0 = __uint_as_float(u0 << 16), v1 = __uint_as_float(u1 << 16);
      float v2 = __uint_as_float(u2 << 16), v3 = __uint_as_float(u3 << 16);
      float v4 = __uint_as_float(u4 << 16), v5 = __uint_as_float(u5 << 16);
      float v6 = __uint_as_float(u6 << 16), v7 = __uint_as_float(u7 << 16);
      acc.x += v0 * __uint_as_float(g0 << 16) + v1 * __uint_as_float(g1 << 16)
             + v2 * __uint_as_float(g2 << 16) + v3 * __uint_as_float(g3 << 16)
             + v4 * __uint_as_float(g4 << 16) + v5 * __uint_as_float(g5 << 16)
             + v6 * __uint_as_float(g6 << 16) + v7 * __uint_as_float(g7 << 16);
      acc.y += v0 * __uint_as_float(g0 & 0xFFFF0000u) + v1 * __uint_as_float(g1 & 0xFFFF0000u)
             + v2 * __uint_as_float(g2 & 0xFFFF0000u) + v3 * __uint_as_float(g3 & 0xFFFF0000u)
             + v4 * __uint_as_float(g4 & 0xFFFF0000u) + v5 * __uint_as_float(g5 & 0xFFFF0000u)
             + v6 * __uint_as_float(g6 & 0xFFFF0000u) + v7 * __uint_as_float(g7 & 0xFFFF0000u);
    }
    for (; i < e2; i++) {
      unsigned u = epack[i];
      unsigned g = xb[(u >> 16) * 64 + l];
      float v = __uint_as_float(u << 16);
      acc.x += v * __uint_as_float(g << 16);
      acc.y += v * __uint_as_float(g & 0xFFFF0000u);
    }
    Au[(size_t)node * 256 + r * 64 + l] = pack_bf2(acc.x, acc.y);
    tot.x += acc.x;
    tot.y += acc.y;
  }
  float sum = tot.x + tot.y;
  float sq  = tot.x * tot.x + tot.y * tot.y;
  #pragma unroll
  for (int m = 32; m >= 1; m >>= 1) {
    sum += __shfl_xor(sum, m);
    sq  += __shfl_xor(sq,  m);
  }
  float mean = sum * (1.0f / D);
  float var  = sq * (1.0f / D) - mean * mean;
  float rstd = rsqrtf(var + EPS);
  int d = l * 2;
  float o0 = (tot.x - mean) * rstd * gamma[d]     + beta[d];
  float o1 = (tot.y - mean) * rstd * gamma[d + 1] + beta[d + 1];
  Au[(size_t)node * 256 + 192 + l] = pack_bf2(o0, o1);
}

// ---------------------------------------------------------------------------
// K4b: build W^T bf16 [128 cols][512 k]: k<384 from weight, else share_weight
// ---------------------------------------------------------------------------
__global__ __launch_bounds__(256) void build_wt(
    const float* __restrict__ w,    // [384][128]
    const float* __restrict__ shw,  // [128][128]
    unsigned short* __restrict__ WT) { // bf16 [128][512]
  int idx = blockIdx.x * 256 + threadIdx.x;  // 65536
  int k   = idx >> 7;
  int col = idx & 127;
  float v = (k < 384) ? w[k * 128 + col] : shw[(k - 384) * 128 + col];
  WT[col * 512 + k] = (unsigned short)bf16_lo(v);
}

// ---------------------------------------------------------------------------
// K5: bf16 MFMA GEMM.  out = 0.5 * A[50000][512] @ W[512][128] + bias
// BM=64, BN=128 (full), BK=64. 4 waves (2x2), each wave 32 rows x 64 cols.
// ---------------------------------------------------------------------------
__global__ __launch_bounds__(256) void gemm_mfma(
    const char* __restrict__ Ab,    // bf16 [MPAD][512] as bytes
    const char* __restrict__ Bb,    // bf16 [128][512] (W^T) as bytes
    const float* __restrict__ bias, // [128]
    float* __restrict__ out) {      // [NN][128]
  __shared__ __align__(16) char smem[24576];   // As 8KB | Bs 16KB
  char* As = smem;
  char* Bs = smem + 8192;

  int tid  = threadIdx.x;
  int wid  = tid >> 6;
  int lane = tid & 63;
  int wr   = wid >> 1;
  int wc   = wid & 1;
  int row0 = blockIdx.x * 64;

  f32x4 zero = {0.f, 0.f, 0.f, 0.f};
  f32x4 acc[2][4];
  #pragma unroll
  for (int i = 0; i < 2; i++)
    #pragma unroll
    for (int j = 0; j < 4; j++) acc[i][j] = zero;

  for (int kc = 0; kc < 8; kc++) {
    #pragma unroll
    for (int i = 0; i < 2; i++) {
      int c = i * 256 + tid;
      int r = c >> 3, s = c & 7;
      int ss = s ^ (r & 7);
      const void* src = Ab + (size_t)(row0 + r) * 1024 + kc * 128 + ss * 16;
      void* dst = As + i * 4096 + wid * 1024;
      gload16(src, dst);
    }
    #pragma unroll
    for (int i = 0; i < 4; i++) {
      int c = i * 256 + tid;
      int r = c >> 3, s = c & 7;
      int ss = s ^ (r & 7);
      const void* src = Bb + (size_t)r * 1024 + kc * 128 + ss * 16;
      void* dst = Bs + i * 4096 + wid * 1024;
      gload16(src, dst);
    }
    __syncthreads();

    #pragma unroll
    for (int ks = 0; ks < 2; ks++) {
      bf16x8 afrag[2], bfrag[4];
      int sg = ks * 4 + (lane >> 4);
      #pragma unroll
      for (int rb = 0; rb < 2; rb++) {
        int r = wr * 32 + rb * 16 + (lane & 15);
        afrag[rb] = *(const bf16x8*)(As + r * 128 + (sg ^ (r & 7)) * 16);
      }
      #pragma unroll
      for (int cb = 0; cb < 4; cb++) {
        int col = wc * 64 + cb * 16 + (lane & 15);
        bfrag[cb] = *(const bf16x8*)(Bs + col * 128 + (sg ^ (col & 7)) * 16);
      }
      #pragma unroll
      for (int rb = 0; rb < 2; rb++)
        #pragma unroll
        for (int cb = 0; cb < 4; cb++)
          acc[rb][cb] = __builtin_amdgcn_mfma_f32_16x16x32_bf16(
              afrag[rb], bfrag[cb], acc[rb][cb], 0, 0, 0);
    }
    __syncthreads();
  }

  #pragma unroll
  for (int rb = 0; rb < 2; rb++) {
    #pragma unroll
    for (int cb = 0; cb < 4; cb++) {
      int col = wc * 64 + cb * 16 + (lane & 15);
      float bv = bias[col];
      #pragma unroll
      for (int r = 0; r < 4; r++) {
        int grow = row0 + wr * 32 + rb * 16 + (lane >> 4) * 4 + r;
        if (grow < NN) out[(size_t)grow * 128 + col] = 0.5f * acc[rb][cb][r] + bv;
      }
    }
  }
}

// ---------------------------------------------------------------------------
extern "C" void kernel_launch(void* const* d_in, const int* in_sizes, int n_in,
                              void* d_out, int out_size, void* d_ws, size_t ws_size,
                              hipStream_t stream) {
  const float* input  = (const float*)d_in[0];
  const int*   arows  = (const int*)  d_in[1];
  const int*   acols  = (const int*)  d_in[2];
  const float* avals  = (const float*)d_in[3];
  const float* weight = (const float*)d_in[4];
  const float* shw    = (const float*)d_in[5];
  const float* bias   = (const float*)d_in[6];
  const float* gamma  = (const float*)d_in[7];
  const float* beta   = (const float*)d_in[8];
  float* out = (float*)d_out;

  // Workspace layout (~95.5 MB):
  //   A      : MPAD*512 bf16      = 51.25 MB
  //   WT     : 128*512 bf16       = 128 KB
  //   xb     : NN*64 u32          = 12.8 MB
  //   pedges : PART*CAP uint2     = 20.97 MB
  //   epack  : NE u32             = 9.6 MB
  //   off    : RN+1 ints ; pcur : PART ; pbase : PART
  char* ws = (char*)d_ws;
  char*  Abf   = ws;                         ws += (size_t)MPAD * KK * 2;
  unsigned short* WT = (unsigned short*)ws;  ws += (size_t)128 * KK * 2;
  unsigned* xb  = (unsigned*)ws;             ws += (size_t)NN * 64 * 4;
  uint2* pedges = (uint2*)ws;                ws += (size_t)PART * CAP * sizeof(uint2);
  unsigned* epack = (unsigned*)ws;           ws += (size_t)NE * 4;
  int*   off   = (int*)ws;                   ws += ((size_t)RN + 4) * sizeof(int);
  int*   pcur  = (int*)ws;                   ws += (size_t)PART * sizeof(int);
  int*   pbase = (int*)ws;                   ws += (size_t)PART * sizeof(int);

  hipMemsetAsync(pcur, 0, (size_t)PART * sizeof(int), stream);
  build_wt   <<<256, 256, 0, stream>>>(weight, shw, WT);
  build_xb   <<<(NN * 64 + 255) / 256, 256, 0, stream>>>(input, xb);
  part_split <<<(NE + EPB - 1) / EPB, 256, 0, stream>>>(arows, acols, avals,
                                                        pcur, pedges);
  psum       <<<1, 64, 0, stream>>>(pcur, pbase, off);
  sort_part  <<<PART, 256, 0, stream>>>(pedges, pcur, pbase, off, epack);
  gather_ln  <<<(NN + 3) / 4, 256, 0, stream>>>(xb, epack, off, gamma, beta,
                                                (unsigned*)Abf);
  gemm_mfma  <<<MPAD / 64, 256, 0, stream>>>(Abf, (const char*)WT, bias, out);
}

// Round 9
// 185.746 us; speedup vs baseline: 22.8890x; 1.1157x over previous
//
#include <hip/hip_runtime.h>

// Problem constants (fixed by the reference)
constexpr int NN  = 50000;   // nodes
constexpr int NNZ = 800000;  // edges per relation
constexpr int RR  = 3;       // relations
constexpr int D   = 128;     // feature dim (in == out)
constexpr int RN  = RR * NN; // fine buckets (150000)
constexpr int NE  = RR * NNZ;
constexpr int KK  = 512;     // concat K: 3*128 support + 128 layernorm
constexpr int MPAD = 50048;  // 782 * 64, padded row count for A
constexpr int PART = 256;    // coarse partitions (1 sort block per CU)
constexpr int PSZ  = (RN + PART - 1) / PART;  // 586 buckets per partition
constexpr int CAP  = 10240;  // partition capacity (mean 9375, sd ~97)
constexpr int EPB  = 2048;   // edges per part_split block
constexpr int CAPB = 24;     // per-block per-partition staging (mean 8, +5.7 sigma)
constexpr float EPS = 1e-6f;

using bf16x8 = __attribute__((ext_vector_type(8))) __bf16;
using f32x4  = __attribute__((ext_vector_type(4))) float;

// RNE f32 -> bf16 packing helpers (NaN not possible here)
__device__ __forceinline__ unsigned pack_bf2(float a, float b) {
  unsigned ua = __float_as_uint(a); ua = (ua + (0x7FFFu + ((ua >> 16) & 1))) >> 16;
  unsigned ub = __float_as_uint(b); ub = (ub + (0x7FFFu + ((ub >> 16) & 1))) >> 16;
  return ua | (ub << 16);
}
__device__ __forceinline__ unsigned bf16_lo(float a) {
  unsigned ua = __float_as_uint(a);
  return (ua + (0x7FFFu + ((ua >> 16) & 1))) >> 16;
}
__device__ __forceinline__ float blo(unsigned u) { return __uint_as_float(u << 16); }
__device__ __forceinline__ float bhi(unsigned u) { return __uint_as_float(u & 0xFFFF0000u); }

__device__ __forceinline__ void gload16(const void* g, void* l) {
  __builtin_amdgcn_global_load_lds(
      (const __attribute__((address_space(1))) unsigned int*)g,
      (__attribute__((address_space(3))) unsigned int*)l, 16, 0, 0);
}

// ---------------------------------------------------------------------------
// K1: multisplit. Edges -> 256 coarse partitions via LDS ranking + staging.
// ---------------------------------------------------------------------------
__global__ __launch_bounds__(256) void part_split(
    const int*   __restrict__ rows,
    const int*   __restrict__ cols,
    const float* __restrict__ vals,
    int* __restrict__ pcur,       // [PART]
    uint2* __restrict__ pedges) { // [PART*CAP]
  __shared__ int lcur[PART], lbase[PART];
  __shared__ uint2 lbuf[PART][CAPB];          // 48 KB staging
  int t = threadIdx.x;
  lcur[t] = 0;
  __syncthreads();
  int e0 = blockIdx.x * EPB;
  constexpr int EPT = EPB / 256;              // 8 edges per thread
  int ovf_pe[EPT], ovf_rank[EPT];             // rare overflow path
  uint2 ovf_val[EPT];
  #pragma unroll
  for (int j = 0; j < EPT; j++) {
    ovf_pe[j] = -1;
    int e = e0 + j * 256 + t;
    if (e < NE) {
      int r = (e >= 2 * NNZ) ? 2 : (e >= NNZ ? 1 : 0);
      int b = r * NN + rows[e];
      int p = b / PSZ;                        // magic-mul div
      unsigned pay = ((unsigned)cols[e] << 16) | bf16_lo(vals[e]);
      int rank = atomicAdd(&lcur[p], 1);
      if (rank < CAPB) {
        lbuf[p][rank] = make_uint2((unsigned)b, pay);
      } else {
        ovf_pe[j] = p; ovf_rank[j] = rank;
        ovf_val[j] = make_uint2((unsigned)b, pay);
      }
    }
  }
  __syncthreads();
  lbase[t] = atomicAdd(&pcur[t], lcur[t]);
  __syncthreads();
  int wid = t >> 6, l = t & 63;
  for (int q = 0; q < 64; q++) {
    int p = wid * 64 + q;
    int n = min(lcur[p], CAPB);
    uint2* dst = pedges + (size_t)p * CAP + lbase[p];
    for (int i = l; i < n; i += 64) dst[i] = lbuf[p][i];
  }
  #pragma unroll
  for (int j = 0; j < EPT; j++)
    if (ovf_pe[j] >= 0)
      pedges[(size_t)ovf_pe[j] * CAP + lbase[ovf_pe[j]] + ovf_rank[j]] = ovf_val[j];
}

// ---------------------------------------------------------------------------
// K2: exclusive scan of the 256 partition totals (single wave, 4 chunks).
// ---------------------------------------------------------------------------
__global__ __launch_bounds__(64) void psum(
    const int* __restrict__ pcur, int* __restrict__ pbase, int* __restrict__ off) {
  int l = threadIdx.x;
  int carry = 0;
  for (int base = 0; base < PART; base += 64) {
    int v = pcur[base + l];
    int inc = v;
    #pragma unroll
    for (int s = 1; s < 64; s <<= 1) {
      int u = __shfl_up(inc, s);
      if (l >= s) inc += u;
    }
    pbase[base + l] = inc - v + carry;
    carry += __shfl(inc, 63);
  }
  if (l == 0) off[RN] = NE;
}

// ---------------------------------------------------------------------------
// K3: per-partition LDS counting sort (256 blocks).
// ---------------------------------------------------------------------------
__global__ __launch_bounds__(256) void sort_part(
    const uint2* __restrict__ pedges,
    const int*   __restrict__ pcur,
    const int*   __restrict__ pbase,
    int* __restrict__ off,
    unsigned* __restrict__ epack) {
  __shared__ int sc[PSZ];
  __shared__ int sdata[256];
  int p = blockIdx.x;
  int t = threadIdx.x;
  int bb = p * PSZ;
  int nbuck = min(PSZ, RN - bb);
  int n = pcur[p];
  int gbase = pbase[p];
  const uint2* src = pedges + (size_t)p * CAP;

  for (int i = t; i < nbuck; i += 256) sc[i] = 0;
  __syncthreads();
  for (int i = t; i < n; i += 256)
    atomicAdd(&sc[src[i].x - bb], 1);
  __syncthreads();

  constexpr int PER = (PSZ + 255) / 256;    // 3
  int lo = t * PER, hi = min(lo + PER, nbuck);
  int s = 0;
  for (int i = lo; i < hi; i++) s += sc[i];
  sdata[t] = s;
  __syncthreads();
  #pragma unroll
  for (int step = 1; step < 256; step <<= 1) {
    int v = (t >= step) ? sdata[t - step] : 0;
    __syncthreads();
    sdata[t] += v;
    __syncthreads();
  }
  int run = gbase + sdata[t] - s;
  for (int i = lo; i < hi; i++) {
    int c = sc[i];
    sc[i] = run;
    off[bb + i] = run;
    run += c;
  }
  __syncthreads();

  for (int i = t; i < n; i += 256) {
    uint2 ed = src[i];
    int pos = atomicAdd(&sc[ed.x - bb], 1);
    epack[pos] = ed.y;
  }
}

// ---------------------------------------------------------------------------
// K4pre: x -> bf16 pairs. xb[node*64 + w] = bf16x2(x[node][2w], x[node][2w+1])
// ---------------------------------------------------------------------------
__global__ __launch_bounds__(256) void build_xb(
    const float* __restrict__ x, unsigned* __restrict__ xb) {
  int i = blockIdx.x * 256 + threadIdx.x;
  if (i >= NN * 64) return;
  float2 v = ((const float2*)x)[i];
  xb[i] = pack_bf2(v.x, v.y);
}

// ---------------------------------------------------------------------------
// K4: gather SpMM (3 relations) + sum + LayerNorm, fused.
// One wave per node. 16 lanes per edge (4 edge-groups g=lane>>4); lane
// q=lane&15 owns dims 8q..8q+7 via one dwordx4 per edge-group. Edge words
// fetched cooperatively (one vector load per <=64 edges) and broadcast via
// shfl -- no dependent uniform-load chain, 4x fewer gather instructions.
// ---------------------------------------------------------------------------
__global__ __launch_bounds__(256) void gather_ln(
    const unsigned* __restrict__ xb,    // [NN][64] bf16x2
    const unsigned* __restrict__ epack, // [NE] col16|bf16val, bucket-sorted
    const int*      __restrict__ off,   // [RN+1]
    const float* __restrict__ gamma,
    const float* __restrict__ beta,
    unsigned* __restrict__ Au) {        // A as uint view: [MPAD][256]
  int node = blockIdx.x * 4 + (threadIdx.x >> 6);
  if (node >= NN) return;
  int lane = threadIdx.x & 63;
  int g  = lane >> 4;        // edge subgroup 0..3
  int q  = lane & 15;        // dim slice: dims 8q..8q+7
  int q4 = q * 4;            // u32 offset within row

  float l0=0,l1=0,l2=0,l3=0,l4=0,l5=0,l6=0,l7=0;   // LN accumulator (sum slabs)

  #pragma unroll
  for (int r = 0; r < RR; r++) {
    int b = r * NN + node;
    int s = off[b], e2 = off[b + 1];
    float a0=0,a1=0,a2=0,a3=0,a4=0,a5=0,a6=0,a7=0; // this lane, group-g edges

    for (int i0 = s; i0 < e2; i0 += 64) {
      int navail = min(64, e2 - i0);
      unsigned ep = (lane < navail) ? epack[i0 + lane] : 0u;
      int c0 = 0;
      // main: 8 edges (2 per group) per iteration, both gathers in flight
      for (; c0 + 8 <= navail; c0 += 8) {
        unsigned ua = __shfl(ep, c0 + g);
        unsigned ub = __shfl(ep, c0 + 4 + g);
        uint4 ga = *(const uint4*)(xb + (size_t)(ua >> 16) * 64 + q4);
        uint4 gb = *(const uint4*)(xb + (size_t)(ub >> 16) * 64 + q4);
        float va = blo(ua), vb = blo(ub);
        a0 += va * blo(ga.x); a1 += va * bhi(ga.x);
        a2 += va * blo(ga.y); a3 += va * bhi(ga.y);
        a4 += va * blo(ga.z); a5 += va * bhi(ga.z);
        a6 += va * blo(ga.w); a7 += va * bhi(ga.w);
        a0 += vb * blo(gb.x); a1 += vb * bhi(gb.x);
        a2 += vb * blo(gb.y); a3 += vb * bhi(gb.y);
        a4 += vb * blo(gb.z); a5 += vb * bhi(gb.z);
        a6 += vb * blo(gb.w); a7 += vb * bhi(gb.w);
      }
      // tail: 4-edge chunks, invalid groups contribute v=0
      for (; c0 < navail; c0 += 4) {
        int eidx = c0 + g;
        unsigned u = __shfl(ep, min(eidx, navail - 1));
        float v = (eidx < navail) ? blo(u) : 0.0f;
        uint4 gg = *(const uint4*)(xb + (size_t)(u >> 16) * 64 + q4);
        a0 += v * blo(gg.x); a1 += v * bhi(gg.x);
        a2 += v * blo(gg.y); a3 += v * bhi(gg.y);
        a4 += v * blo(gg.z); a5 += v * bhi(gg.z);
        a6 += v * blo(gg.w); a7 += v * bhi(gg.w);
      }
    }
    // combine the 4 edge-groups: every lane ends with the full slab slice
    #define REDG(x) x += __shfl_xor(x, 16); x += __shfl_xor(x, 32);
    REDG(a0) REDG(a1) REDG(a2) REDG(a3) REDG(a4) REDG(a5) REDG(a6) REDG(a7)
    #undef REDG
    if (g == 0) {
      uint4 w;
      w.x = pack_bf2(a0, a1); w.y = pack_bf2(a2, a3);
      w.z = pack_bf2(a4, a5); w.w = pack_bf2(a6, a7);
      *(uint4*)(Au + (size_t)node * 256 + r * 64 + q4) = w;
    }
    l0 += a0; l1 += a1; l2 += a2; l3 += a3;
    l4 += a4; l5 += a5; l6 += a6; l7 += a7;
  }

  // LayerNorm over the 128-dim summed slab
  float sum = l0+l1+l2+l3+l4+l5+l6+l7;
  float sq  = l0*l0+l1*l1+l2*l2+l3*l3+l4*l4+l5*l5+l6*l6+l7*l7;
  #pragma unroll
  for (int m = 1; m <= 8; m <<= 1) {
    sum += __shfl_xor(sum, m);
    sq  += __shfl_xor(sq,  m);
  }
  float mean = sum * (1.0f / D);
  float var  = sq * (1.0f / D) - mean * mean;
  float rstd = rsqrtf(var + EPS);
  float4 gm0 = *(const float4*)&gamma[8 * q];
  float4 gm1 = *(const float4*)&gamma[8 * q + 4];
  float4 bt0 = *(const float4*)&beta[8 * q];
  float4 bt1 = *(const float4*)&beta[8 * q + 4];
  float o0 = (l0 - mean) * rstd * gm0.x + bt0.x;
  float o1 = (l1 - mean) * rstd * gm0.y + bt0.y;
  float o2 = (l2 - mean) * rstd * gm0.z + bt0.z;
  float o3 = (l3 - mean) * rstd * gm0.w + bt0.w;
  float o4 = (l4 - mean) * rstd * gm1.x + bt1.x;
  float o5 = (l5 - mean) * rstd * gm1.y + bt1.y;
  float o6 = (l6 - mean) * rstd * gm1.z + bt1.z;
  float o7 = (l7 - mean) * rstd * gm1.w + bt1.w;
  if (g == 0) {
    uint4 w;
    w.x = pack_bf2(o0, o1); w.y = pack_bf2(o2, o3);
    w.z = pack_bf2(o4, o5); w.w = pack_bf2(o6, o7);
    *(uint4*)(Au + (size_t)node * 256 + 192 + q4) = w;
  }
}

// ---------------------------------------------------------------------------
// K4b: build W^T bf16 [128 cols][512 k]: k<384 from weight, else share_weight
// ---------------------------------------------------------------------------
__global__ __launch_bounds__(256) void build_wt(
    const float* __restrict__ w,    // [384][128]
    const float* __restrict__ shw,  // [128][128]
    unsigned short* __restrict__ WT) { // bf16 [128][512]
  int idx = blockIdx.x * 256 + threadIdx.x;  // 65536
  int k   = idx >> 7;
  int col = idx & 127;
  float v = (k < 384) ? w[k * 128 + col] : shw[(k - 384) * 128 + col];
  WT[col * 512 + k] = (unsigned short)bf16_lo(v);
}

// ---------------------------------------------------------------------------
// K5: bf16 MFMA GEMM.  out = 0.5 * A[50000][512] @ W[512][128] + bias
// ---------------------------------------------------------------------------
__global__ __launch_bounds__(256) void gemm_mfma(
    const char* __restrict__ Ab,    // bf16 [MPAD][512] as bytes
    const char* __restrict__ Bb,    // bf16 [128][512] (W^T) as bytes
    const float* __restrict__ bias, // [128]
    float* __restrict__ out) {      // [NN][128]
  __shared__ __align__(16) char smem[24576];   // As 8KB | Bs 16KB
  char* As = smem;
  char* Bs = smem + 8192;

  int tid  = threadIdx.x;
  int wid  = tid >> 6;
  int lane = tid & 63;
  int wr   = wid >> 1;
  int wc   = wid & 1;
  int row0 = blockIdx.x * 64;

  f32x4 zero = {0.f, 0.f, 0.f, 0.f};
  f32x4 acc[2][4];
  #pragma unroll
  for (int i = 0; i < 2; i++)
    #pragma unroll
    for (int j = 0; j < 4; j++) acc[i][j] = zero;

  for (int kc = 0; kc < 8; kc++) {
    #pragma unroll
    for (int i = 0; i < 2; i++) {
      int c = i * 256 + tid;
      int r = c >> 3, s = c & 7;
      int ss = s ^ (r & 7);
      const void* src = Ab + (size_t)(row0 + r) * 1024 + kc * 128 + ss * 16;
      void* dst = As + i * 4096 + wid * 1024;
      gload16(src, dst);
    }
    #pragma unroll
    for (int i = 0; i < 4; i++) {
      int c = i * 256 + tid;
      int r = c >> 3, s = c & 7;
      int ss = s ^ (r & 7);
      const void* src = Bb + (size_t)r * 1024 + kc * 128 + ss * 16;
      void* dst = Bs + i * 4096 + wid * 1024;
      gload16(src, dst);
    }
    __syncthreads();

    #pragma unroll
    for (int ks = 0; ks < 2; ks++) {
      bf16x8 afrag[2], bfrag[4];
      int sg = ks * 4 + (lane >> 4);
      #pragma unroll
      for (int rb = 0; rb < 2; rb++) {
        int r = wr * 32 + rb * 16 + (lane & 15);
        afrag[rb] = *(const bf16x8*)(As + r * 128 + (sg ^ (r & 7)) * 16);
      }
      #pragma unroll
      for (int cb = 0; cb < 4; cb++) {
        int col = wc * 64 + cb * 16 + (lane & 15);
        bfrag[cb] = *(const bf16x8*)(Bs + col * 128 + (sg ^ (col & 7)) * 16);
      }
      #pragma unroll
      for (int rb = 0; rb < 2; rb++)
        #pragma unroll
        for (int cb = 0; cb < 4; cb++)
          acc[rb][cb] = __builtin_amdgcn_mfma_f32_16x16x32_bf16(
              afrag[rb], bfrag[cb], acc[rb][cb], 0, 0, 0);
    }
    __syncthreads();
  }

  #pragma unroll
  for (int rb = 0; rb < 2; rb++) {
    #pragma unroll
    for (int cb = 0; cb < 4; cb++) {
      int col = wc * 64 + cb * 16 + (lane & 15);
      float bv = bias[col];
      #pragma unroll
      for (int r = 0; r < 4; r++) {
        int grow = row0 + wr * 32 + rb * 16 + (lane >> 4) * 4 + r;
        if (grow < NN) out[(size_t)grow * 128 + col] = 0.5f * acc[rb][cb][r] + bv;
      }
    }
  }
}

// ---------------------------------------------------------------------------
extern "C" void kernel_launch(void* const* d_in, const int* in_sizes, int n_in,
                              void* d_out, int out_size, void* d_ws, size_t ws_size,
                              hipStream_t stream) {
  const float* input  = (const float*)d_in[0];
  const int*   arows  = (const int*)  d_in[1];
  const int*   acols  = (const int*)  d_in[2];
  const float* avals  = (const float*)d_in[3];
  const float* weight = (const float*)d_in[4];
  const float* shw    = (const float*)d_in[5];
  const float* bias   = (const float*)d_in[6];
  const float* gamma  = (const float*)d_in[7];
  const float* beta   = (const float*)d_in[8];
  float* out = (float*)d_out;

  char* ws = (char*)d_ws;
  char*  Abf   = ws;                         ws += (size_t)MPAD * KK * 2;
  unsigned short* WT = (unsigned short*)ws;  ws += (size_t)128 * KK * 2;
  unsigned* xb  = (unsigned*)ws;             ws += (size_t)NN * 64 * 4;
  uint2* pedges = (uint2*)ws;                ws += (size_t)PART * CAP * sizeof(uint2);
  unsigned* epack = (unsigned*)ws;           ws += (size_t)NE * 4;
  int*   off   = (int*)ws;                   ws += ((size_t)RN + 4) * sizeof(int);
  int*   pcur  = (int*)ws;                   ws += (size_t)PART * sizeof(int);
  int*   pbase = (int*)ws;                   ws += (size_t)PART * sizeof(int);

  hipMemsetAsync(pcur, 0, (size_t)PART * sizeof(int), stream);
  build_wt   <<<256, 256, 0, stream>>>(weight, shw, WT);
  build_xb   <<<(NN * 64 + 255) / 256, 256, 0, stream>>>(input, xb);
  part_split <<<(NE + EPB - 1) / EPB, 256, 0, stream>>>(arows, acols, avals,
                                                        pcur, pedges);
  psum       <<<1, 64, 0, stream>>>(pcur, pbase, off);
  sort_part  <<<PART, 256, 0, stream>>>(pedges, pcur, pbase, off, epack);
  gather_ln  <<<(NN + 3) / 4, 256, 0, stream>>>(xb, epack, off, gamma, beta,
                                                (unsigned*)Abf);
  gemm_mfma  <<<MPAD / 64, 256, 0, stream>>>(Abf, (const char*)WT, bias, out);
}